// Round 23
// baseline (900.763 us; speedup 1.0000x reference)
//
#include <hip/hip_runtime.h>
#include <stdint.h>

#define TT 128
#define BB 128
#define OBSD 512
#define HID 1024
#define DPAR 24
#define BUCKCAP 16384

typedef _Float16 f16;
typedef _Float16 f16x8 __attribute__((ext_vector_type(8)));
typedef _Float16 f16x4 __attribute__((ext_vector_type(4)));
typedef float f32x4 __attribute__((ext_vector_type(4)));

__device__ __forceinline__ f32x4 mfma16(f16x8 a, f16x8 b, f32x4 c){
  return __builtin_amdgcn_mfma_f32_16x16x32_f16(a, b, c, 0, 0, 0);
}
__device__ __forceinline__ void gload16(const void* g, void* l){
  __builtin_amdgcn_global_load_lds(
      (const __attribute__((address_space(1))) unsigned int*)g,
      (__attribute__((address_space(3))) unsigned int*)l, 16, 0, 0);
}

// ---- prep: world_state f32 -> f16 ----
__global__ void k_ws_to_f16(const float* __restrict__ src, f16* __restrict__ dst, int n4){
  int i = blockIdx.x * blockDim.x + threadIdx.x;
  if (i < n4){
    float4 v = *reinterpret_cast<const float4*>(src + (size_t)i * 4);
    dst[(size_t)i*4 + 0] = (f16)v.x; dst[(size_t)i*4 + 1] = (f16)v.y;
    dst[(size_t)i*4 + 2] = (f16)v.z; dst[(size_t)i*4 + 3] = (f16)v.w;
  }
}

// ---- prep: transpose f32 [KD][C] (row stride srcStride) -> f16 dst[C][KD] ----
__global__ void k_prep_bt(const float* __restrict__ s0, int srcStride,
                          f16* __restrict__ dst, int KD){
  __shared__ f16 sm[64][65];
  int k0 = blockIdx.x * 64, c0 = blockIdx.y * 64;
  for (int it = 0; it < 16; ++it){
    int idx = it * 256 + threadIdx.x;
    int kr = idx >> 6, cc = idx & 63;
    sm[kr][cc] = (f16)s0[(size_t)(k0 + kr) * srcStride + (c0 + cc)];
  }
  __syncthreads();
  for (int it = 0; it < 16; ++it){
    int idx = it * 256 + threadIdx.x;
    int cr = idx >> 6, kc = idx & 63;
    dst[(size_t)(c0 + cr) * KD + (k0 + kc)] = sm[kc][cr];
  }
}

// ---- prep: bt2[c][k] = k<1024 ? Wi[k][c] : Wh[k-1024][c]; c<3072, k<2048 ----
__global__ void k_prep_bt2(const float* __restrict__ wi, const float* __restrict__ wh,
                           f16* __restrict__ dst){
  __shared__ f16 sm[64][65];
  int k0 = blockIdx.x * 64, c0 = blockIdx.y * 64;
  const float* src = (k0 < 1024) ? wi : wh;
  int kb = (k0 < 1024) ? k0 : k0 - 1024;
  for (int it = 0; it < 16; ++it){
    int idx = it * 256 + threadIdx.x;
    int kr = idx >> 6, cc = idx & 63;
    sm[kr][cc] = (f16)src[(size_t)(kb + kr) * 3072 + (c0 + cc)];
  }
  __syncthreads();
  for (int it = 0; it < 16; ++it){
    int idx = it * 256 + threadIdx.x;
    int cr = idx >> 6, kc = idx & 63;
    dst[(size_t)(c0 + cr) * 2048 + (k0 + kc)] = sm[kc][cr];
  }
}

// ---- segmentation v6: (t,b)-parallel, O(1)/thread bit math, ballot ranks ----
__global__ void k_seg(const int* __restrict__ dones, int* __restrict__ cnt,
                      int* __restrict__ rowlist, int* __restrict__ zlist,
                      int* __restrict__ chains){
  __shared__ unsigned long long sm_m[2];
  __shared__ int cntw[2][26];
  __shared__ int lbase[26];
  const int b = blockIdx.x, t = threadIdx.x;
  const int wv = t >> 6, lane = t & 63;
  bool pred = (t >= 1) && (dones[t*BB + b] != 0);
  unsigned long long bal = __ballot(pred);
  if (lane == 0) sm_m[wv] = bal;
  __syncthreads();
  const unsigned long long m0 = sm_m[0], m1 = sm_m[1];
  const bool d0 = (dones[b] != 0);
  int s, e;
  if (t < 64){
    unsigned long long msk = (t == 63) ? ~0ull : ((1ull << (t+1)) - 1);
    unsigned long long lo = m0 & msk;
    s = lo ? 63 - __builtin_clzll(lo) : 0;
    unsigned long long rem = m0 & ~msk;
    if (rem) e = __builtin_ctzll(rem);
    else if (m1) e = 64 + __builtin_ctzll(m1);
    else e = TT;
  } else {
    int u = t - 64;
    unsigned long long msk = (u == 63) ? ~0ull : ((1ull << (u+1)) - 1);
    unsigned long long hi = m1 & msk;
    if (hi) s = 64 + 63 - __builtin_clzll(hi);
    else s = m0 ? 63 - __builtin_clzll(m0) : 0;
    unsigned long long rem = m1 & ~msk;
    e = rem ? 64 + __builtin_ctzll(rem) : TT;
  }
  const int d = t - s;
  int my_d;
  if (d == 0)            my_d = (s == 0 && !d0) ? 0 : 24;
  else if (d < DPAR)     my_d = d;
  else if (d == DPAR)    my_d = 25;
  else                   my_d = 26;
  int my_rank = 0;
  for (int d2 = 0; d2 < 26; ++d2){
    unsigned long long mk = __ballot(my_d == d2);
    if (my_d == d2) my_rank = __popcll(mk & ((1ull << lane) - 1));
    if (lane == 0) cntw[wv][d2] = __popcll(mk);
  }
  __syncthreads();
  if (wv == 1 && my_d < 26) my_rank += cntw[0][my_d];
  if (t < 26){
    int tot = cntw[0][t] + cntw[1][t];
    lbase[t] = tot ? atomicAdd(&cnt[t], tot) : 0;
  }
  __syncthreads();
  if (my_d < 24){
    rowlist[my_d*BUCKCAP + lbase[my_d] + my_rank] = (t << 7) | b;
  } else if (my_d == 24){
    zlist[lbase[24] + my_rank] = (t << 7) | b;
  } else if (my_d == 25){
    int c = lbase[25] + my_rank;
    chains[c*3+0] = b; chains[c*3+1] = s; chains[c*3+2] = e - s;
  }
}

// ---- emb = relu(ws @ W_emb + b_emb): m97 + 2-phase dbuf, K=512 (8 kt) ----
__global__ __launch_bounds__(256)
void k_emb(const f16* __restrict__ A, const f16* __restrict__ Bt,
           const float* __restrict__ bias, f16* __restrict__ outb){
  __shared__ __attribute__((aligned(16))) char smem[65536];
  int tid = threadIdx.x;
  int w = tid >> 6, lane = tid & 63;
  int wm = w >> 1, wn = w & 1;
  int bid = blockIdx.x;                       // 1024 = 128 Mb x 8 Nb
  int vid = (bid & 7) * 128 + (bid >> 3);
  int Mb = (vid >> 3) * 128, Nb = (vid & 7) * 128;
  int la = lane & 15, lk = (lane >> 4) * 8;
  f32x4 acc[4][4] = {};
  int pr[4], pc16[4];
  #pragma unroll
  for (int q = 0; q < 4; ++q){
    int P = (w*4 + q)*1024 + lane*16;
    int r = P >> 7;
    pr[q] = r;
    pc16[q] = ((P & 127) ^ ((r & 7) << 4)) >> 4;
  }
  #pragma unroll
  for (int q = 0; q < 4; ++q){
    gload16(A  + (size_t)(Mb + pr[q])*OBSD + pc16[q]*8, smem + (w*4 + q)*1024);
    gload16(Bt + (size_t)(Nb + pr[q])*OBSD + pc16[q]*8, smem + 16384 + (w*4 + q)*1024);
  }
  __syncthreads();
  for (int kt = 0; kt < 8; ++kt){
    const int cb = (kt & 1) * 32768;
    if (kt + 1 < 8){
      const int pb = ((kt + 1) & 1) * 32768;
      #pragma unroll
      for (int q = 0; q < 4; ++q){
        gload16(A  + (size_t)(Mb + pr[q])*OBSD + (kt+1)*64 + pc16[q]*8,
                smem + pb + (w*4 + q)*1024);
        gload16(Bt + (size_t)(Nb + pr[q])*OBSD + (kt+1)*64 + pc16[q]*8,
                smem + pb + 16384 + (w*4 + q)*1024);
      }
    }
    #pragma unroll
    for (int kk = 0; kk < 64; kk += 32){
      f16x8 av[4], bv[4];
      #pragma unroll
      for (int m = 0; m < 4; ++m){
        int r = wm*64 + m*16 + la;
        av[m] = *reinterpret_cast<const f16x8*>(
            smem + cb + r*128 + (((kk + lk)*2) ^ ((r & 7) << 4)));
      }
      #pragma unroll
      for (int n = 0; n < 4; ++n){
        int r = wn*64 + n*16 + la;
        bv[n] = *reinterpret_cast<const f16x8*>(
            smem + cb + 16384 + r*128 + (((kk + lk)*2) ^ ((r & 7) << 4)));
      }
      #pragma unroll
      for (int m = 0; m < 4; ++m)
        #pragma unroll
        for (int n = 0; n < 4; ++n)
          acc[m][n] = mfma16(av[m], bv[n], acc[m][n]);
    }
    __syncthreads();
  }
  for (int mi = 0; mi < 4; ++mi) for (int ni = 0; ni < 4; ++ni){
    int col = Nb + wn*64 + ni*16 + la;
    float bb = bias[col];
    for (int i = 0; i < 4; ++i){
      int row = Mb + wm*64 + mi*16 + (lane >> 4)*4 + i;
      float v = acc[mi][ni][i] + bb;
      outb[(size_t)row * HID + col] = (f16)(v > 0.f ? v : 0.f);
    }
  }
}

// ---- xi = emb @ Wi + bi: m97 + 2-phase dbuf (128x128, BK=64, 16 kt) ----
__global__ __launch_bounds__(256)
void k_xi(const f16* __restrict__ A, const f16* __restrict__ Bt,
          const float* __restrict__ bias, f16* __restrict__ outb){
  __shared__ __attribute__((aligned(16))) char smem[65536];
  int tid = threadIdx.x;
  int w = tid >> 6, lane = tid & 63;
  int wm = w >> 1, wn = w & 1;
  int bid = blockIdx.x;                       // 3072 = 128 Mb x 24 Nb
  int vid = (bid & 7) * 384 + (bid >> 3);
  int Mb = (vid / 24) * 128, Nb = (vid % 24) * 128;
  int la = lane & 15, lk = (lane >> 4) * 8;
  f32x4 acc[4][4] = {};
  int pr[4], pc16[4];
  #pragma unroll
  for (int q = 0; q < 4; ++q){
    int P = (w*4 + q)*1024 + lane*16;
    int r = P >> 7;
    pr[q] = r;
    pc16[q] = ((P & 127) ^ ((r & 7) << 4)) >> 4;
  }
  #pragma unroll
  for (int q = 0; q < 4; ++q){
    gload16(A  + (size_t)(Mb + pr[q])*HID  + pc16[q]*8, smem + (w*4 + q)*1024);
    gload16(Bt + (size_t)(Nb + pr[q])*2048 + pc16[q]*8, smem + 16384 + (w*4 + q)*1024);
  }
  __syncthreads();
  for (int kt = 0; kt < 16; ++kt){
    const int cb = (kt & 1) * 32768;
    if (kt + 1 < 16){
      const int pb = ((kt + 1) & 1) * 32768;
      #pragma unroll
      for (int q = 0; q < 4; ++q){
        gload16(A  + (size_t)(Mb + pr[q])*HID  + (kt+1)*64 + pc16[q]*8,
                smem + pb + (w*4 + q)*1024);
        gload16(Bt + (size_t)(Nb + pr[q])*2048 + (kt+1)*64 + pc16[q]*8,
                smem + pb + 16384 + (w*4 + q)*1024);
      }
    }
    #pragma unroll
    for (int kk = 0; kk < 64; kk += 32){
      f16x8 av[4], bv[4];
      #pragma unroll
      for (int m = 0; m < 4; ++m){
        int r = wm*64 + m*16 + la;
        av[m] = *reinterpret_cast<const f16x8*>(
            smem + cb + r*128 + (((kk + lk)*2) ^ ((r & 7) << 4)));
      }
      #pragma unroll
      for (int n = 0; n < 4; ++n){
        int r = wn*64 + n*16 + la;
        bv[n] = *reinterpret_cast<const f16x8*>(
            smem + cb + 16384 + r*128 + (((kk + lk)*2) ^ ((r & 7) << 4)));
      }
      #pragma unroll
      for (int m = 0; m < 4; ++m)
        #pragma unroll
        for (int n = 0; n < 4; ++n)
          acc[m][n] = mfma16(av[m], bv[n], acc[m][n]);
    }
    __syncthreads();
  }
  for (int mi = 0; mi < 4; ++mi) for (int ni = 0; ni < 4; ++ni){
    int col = Nb + wn*64 + ni*16 + la;
    float bb = bias[col];
    for (int i = 0; i < 4; ++i){
      int row = Mb + wm*64 + mi*16 + (lane >> 4)*4 + i;
      outb[(size_t)row * 3072 + col] = (f16)(acc[mi][ni][i] + bb);
    }
  }
}

// ---- h-zero rows: h = (1-z)*n, straight from xi (no GEMM) ----
__global__ __launch_bounds__(256)
void k_h0(const int* __restrict__ cnt, const int* __restrict__ zlist,
          const f16* __restrict__ xi, const float* __restrict__ bhn_p,
          f16* __restrict__ y, float* __restrict__ hout){
  int nz = cnt[24];
  int tid = threadIdx.x;
  for (int ridx = blockIdx.x; ridx < nz; ridx += gridDim.x){
    int tb = zlist[ridx];
    int t = tb >> 7, b = tb & 127;
    size_t rb = ((size_t)t*BB + b) * 3072;
    int c0 = tid * 4;
    f16x4 xr = *reinterpret_cast<const f16x4*>(xi + rb + c0);
    f16x4 xz = *reinterpret_cast<const f16x4*>(xi + rb + 1024 + c0);
    f16x4 xn = *reinterpret_cast<const f16x4*>(xi + rb + 2048 + c0);
    f16x4 o;
    #pragma unroll
    for (int u = 0; u < 4; ++u){
      float r = 1.f / (1.f + expf(-(float)xr[u]));
      float z = 1.f / (1.f + expf(-(float)xz[u]));
      float n = tanhf((float)xn[u] + r * bhn_p[c0 + u]);
      float h = (1.f - z) * n;
      o[u] = (f16)h;
      if (t == TT - 1) hout[(size_t)b*HID + c0 + u] = h;
    }
    *reinterpret_cast<f16x4*>(y + ((size_t)t*BB + b)*HID + c0) = o;
  }
}

// ---- depth (small, count<=~1024 expected; correct for any count):
// 16 rows x 32 hcols/block, 8 waves = 2 cs x 4 kq, LDS reduce. 32KB LDS. ----
__global__ __launch_bounds__(512)
void k_depth(int j, const int* __restrict__ cnt, const int* __restrict__ rowlist_g,
             const f16* __restrict__ xi, const f16* __restrict__ bt2,
             const float* __restrict__ bhn_p, const float* __restrict__ hidden0,
             f16* __restrict__ y, float* __restrict__ hout){
  __shared__ __attribute__((aligned(16))) char smem[32768];
  const int count = cnt[j];
  if (count <= 0) return;
  const int* rowlist = rowlist_g + (size_t)j * BUCKCAP;
  const int tid = threadIdx.x;
  const int lane = tid & 63;
  const int w = tid >> 6;
  const int bid = blockIdx.x;
  const int la = lane & 15, lk = (lane >> 4) * 8;
  float* red = (float*)smem;
  const int vid = (bid & 7) * 128 + (bid >> 3);
  const int cs2 = vid >> 5;
  const int rgs = vid & 31;
  const int cg = w >> 2, kq = w & 3;
  const f16* Bq0 = bt2 + (size_t)(          cs2*32 + cg*16 + la)*2048 + 1024 + kq*256 + lk;
  const f16* Bq1 = bt2 + (size_t)(1024 +    cs2*32 + cg*16 + la)*2048 + 1024 + kq*256 + lk;
  const f16* Bq2 = bt2 + (size_t)(2048 +    cs2*32 + cg*16 + la)*2048 + 1024 + kq*256 + lk;
  const int es = tid >> 8, ei = (tid >> 6) & 3, elane = tid & 63;
  const int erow_l = ((elane >> 4) << 2) + ei;
  const int ecol = cs2*32 + es*16 + (elane & 15);
  const float bh = bhn_p[ecol];
  const int nrg = (count + 15) >> 4;
  for (int rg = rgs; rg < nrg; rg += 32){
    __syncthreads();
    #pragma unroll
    for (int it = 0; it < 4; ++it){
      int idx = tid + it*512;
      int r = idx >> 7, part = idx & 127;
      int ridx = rg*16 + r;
      int tb = (ridx < count) ? rowlist[ridx] : -1;
      float4 v = {0.f, 0.f, 0.f, 0.f};
      if (tb >= 0){
        int t = tb >> 7, bb_ = tb & 127;
        if (j > 0){
          v = *reinterpret_cast<const float4*>(y + ((size_t)(t-1)*BB + bb_)*HID + part*8);
        } else {
          const float* s = hidden0 + (size_t)bb_*HID + part*8;
          float4 a0 = *reinterpret_cast<const float4*>(s);
          float4 a1 = *reinterpret_cast<const float4*>(s + 4);
          f16 h8[8] = {(f16)a0.x,(f16)a0.y,(f16)a0.z,(f16)a0.w,
                       (f16)a1.x,(f16)a1.y,(f16)a1.z,(f16)a1.w};
          v = *reinterpret_cast<float4*>(h8);
        }
      }
      *reinterpret_cast<float4*>(smem + ((r*2048 + part*16) ^ ((r & 7) << 4))) = v;
    }
    __syncthreads();
    f32x4 a0 = {}, a1 = {}, a2 = {};
    #pragma unroll
    for (int kk = 0; kk < 256; kk += 32){
      int k = kq*256 + kk + lk;
      f16x8 av = *reinterpret_cast<const f16x8*>(
          smem + ((la*2048 + k*2) ^ ((la & 7) << 4)));
      a0 = mfma16(av, *reinterpret_cast<const f16x8*>(Bq0 + kk), a0);
      a1 = mfma16(av, *reinterpret_cast<const f16x8*>(Bq1 + kk), a1);
      a2 = mfma16(av, *reinterpret_cast<const f16x8*>(Bq2 + kk), a2);
    }
    __syncthreads();
    #pragma unroll
    for (int i = 0; i < 4; ++i){
      red[((((cg*4 + kq)*3 + 0)*64 + lane)*5) + i] = a0[i];
      red[((((cg*4 + kq)*3 + 1)*64 + lane)*5) + i] = a1[i];
      red[((((cg*4 + kq)*3 + 2)*64 + lane)*5) + i] = a2[i];
    }
    __syncthreads();
    int ridx = rg*16 + erow_l;
    if (ridx < count){
      int tb = rowlist[ridx];
      int t = tb >> 7, bb_ = tb & 127;
      float hr = 0.f, hz = 0.f, hn = 0.f;
      #pragma unroll
      for (int kq2 = 0; kq2 < 4; ++kq2){
        hr += red[((((es*4 + kq2)*3 + 0)*64 + elane)*5) + ei];
        hz += red[((((es*4 + kq2)*3 + 1)*64 + elane)*5) + ei];
        hn += red[((((es*4 + kq2)*3 + 2)*64 + elane)*5) + ei];
      }
      size_t rb = ((size_t)t*BB + bb_)*3072 + ecol;
      float hold;
      if (j > 0) hold = (float)y[((size_t)(t-1)*BB + bb_)*HID + ecol];
      else       hold = hidden0[(size_t)bb_*HID + ecol];
      float r = 1.f / (1.f + expf(-((float)xi[rb]        + hr)));
      float z = 1.f / (1.f + expf(-((float)xi[rb + 1024] + hz)));
      float n = tanhf((float)xi[rb + 2048] + r * (hn + bh));
      float hnew = (1.f - z) * n + z * hold;
      y[((size_t)t*BB + bb_)*HID + ecol] = (f16)hnew;
      if (t == TT - 1) hout[(size_t)bb_*HID + ecol] = hnew;
    }
  }
}

// ---- depth (medium, used for j=1,2; correct for any count):
// 32 rows x 256 hcols/block, 8 waves x (2 M-frags x 6 col-frags), full-K.
// A staged 64KB LDS; B direct from L2. 4 col-splits only -> low A re-fetch. ----
__global__ __launch_bounds__(512)
void k_depth_med(int j, const int* __restrict__ cnt, const int* __restrict__ rowlist_g,
                 const f16* __restrict__ xi, const f16* __restrict__ bt2,
                 const float* __restrict__ bhn_p, const float* __restrict__ hidden0,
                 f16* __restrict__ y, float* __restrict__ hout){
  __shared__ __attribute__((aligned(16))) char smem[65536];   // 32 x 1024 f16
  const int count = cnt[j];
  if (count <= 0) return;
  const int* rowlist = rowlist_g + (size_t)j * BUCKCAP;
  const int tid = threadIdx.x;
  const int lane = tid & 63;
  const int w = tid >> 6;                    // 8 waves
  const int bid = blockIdx.x;
  const int la = lane & 15, lk = (lane >> 4) * 8;
  const int vid = (bid & 7) * 128 + (bid >> 3);
  const int cs4 = vid >> 8;                  // [0,4): 256-hcol slice
  const int rgs = vid & 255;                 // rowgroup stride start
  const int colw = cs4*256 + w*32;           // wave's 32-hcol base
  const f16* Bp[6];
  #pragma unroll
  for (int g = 0; g < 3; ++g)
    #pragma unroll
    for (int f = 0; f < 2; ++f)
      Bp[g*2 + f] = bt2 + (size_t)(g*1024 + colw + f*16 + la)*2048 + 1024 + lk;
  const int nrg = (count + 31) >> 5;
  for (int rg = rgs; rg < nrg; rg += 256){
    __syncthreads();                         // prior GEMM smem reads done
    #pragma unroll
    for (int it = 0; it < 8; ++it){          // 512 thr x 8 = 4096 = 32 rows x 128 parts
      int idx = tid + it*512;
      int r = idx >> 7, part = idx & 127;
      int ridx = rg*32 + r;
      int tb = (ridx < count) ? rowlist[ridx] : -1;
      float4 v = {0.f, 0.f, 0.f, 0.f};
      if (tb >= 0){
        int t = tb >> 7, bb_ = tb & 127;
        if (j > 0){
          v = *reinterpret_cast<const float4*>(y + ((size_t)(t-1)*BB + bb_)*HID + part*8);
        } else {
          const float* s = hidden0 + (size_t)bb_*HID + part*8;
          float4 a0 = *reinterpret_cast<const float4*>(s);
          float4 a1 = *reinterpret_cast<const float4*>(s + 4);
          f16 h8[8] = {(f16)a0.x,(f16)a0.y,(f16)a0.z,(f16)a0.w,
                       (f16)a1.x,(f16)a1.y,(f16)a1.z,(f16)a1.w};
          v = *reinterpret_cast<float4*>(h8);
        }
      }
      *reinterpret_cast<float4*>(smem + ((r*2048 + part*16) ^ ((r & 7) << 4))) = v;
    }
    __syncthreads();
    f32x4 acc[2][6] = {};
    #pragma unroll 4
    for (int kk = 0; kk < 1024; kk += 32){
      f16x8 av[2];
      #pragma unroll
      for (int m = 0; m < 2; ++m){
        int r = m*16 + la;
        av[m] = *reinterpret_cast<const f16x8*>(
            smem + ((r*2048 + (kk + lk)*2) ^ ((r & 7) << 4)));
      }
      #pragma unroll
      for (int jf = 0; jf < 6; ++jf){
        f16x8 bv = *reinterpret_cast<const f16x8*>(Bp[jf] + kk);
        acc[0][jf] = mfma16(av[0], bv, acc[0][jf]);
        acc[1][jf] = mfma16(av[1], bv, acc[1][jf]);
      }
    }
    // epilogue: full-K accs in registers; 16 outputs/thread
    #pragma unroll
    for (int f = 0; f < 2; ++f){
      int col = colw + f*16 + la;
      float bh = bhn_p[col];
      #pragma unroll
      for (int m = 0; m < 2; ++m){
        #pragma unroll
        for (int i = 0; i < 4; ++i){
          int lr = m*16 + (lane >> 4)*4 + i;
          int ridx = rg*32 + lr;
          if (ridx >= count) continue;
          int tb = rowlist[ridx];
          int t = tb >> 7, bb_ = tb & 127;
          size_t rb = ((size_t)t*BB + bb_)*3072 + col;
          float hold;
          if (j > 0) hold = (float)y[((size_t)(t-1)*BB + bb_)*HID + col];
          else       hold = hidden0[(size_t)bb_*HID + col];
          float r = 1.f / (1.f + expf(-((float)xi[rb]        + acc[m][0*2+f][i])));
          float z = 1.f / (1.f + expf(-((float)xi[rb + 1024] + acc[m][1*2+f][i])));
          float n = tanhf((float)xi[rb + 2048] + r * (acc[m][2*2+f][i] + bh));
          float hnew = (1.f - z) * n + z * hold;
          y[((size_t)t*BB + bb_)*HID + col] = (f16)hnew;
          if (t == TT - 1) hout[(size_t)bb_*HID + col] = hnew;
        }
      }
    }
  }
}

// ---- sequential tail for chains longer than DPAR (empty for this seed) ----
__global__ __launch_bounds__(256)
void k_tail(const int* __restrict__ cnt, const int* __restrict__ chains,
            const f16* __restrict__ xi, const f16* __restrict__ bt2,
            const float* __restrict__ bhn_p, f16* __restrict__ y,
            float* __restrict__ hout){
  int n = cnt[25];
  __shared__ f16 hs[1024];
  int tid = threadIdx.x;
  for (int c = blockIdx.x; c < n; c += gridDim.x){
    int b = chains[c*3], t0 = chains[c*3+1], len = chains[c*3+2];
    for (int i = tid; i < 1024; i += 256)
      hs[i] = y[((size_t)(t0 + DPAR - 1)*BB + b)*HID + i];
    __syncthreads();
    for (int t = t0 + DPAR; t < t0 + len; ++t){
      float tmp[4];
      #pragma unroll
      for (int u = 0; u < 4; ++u){
        int col = tid*4 + u;
        float s_r = 0.f, s_z = 0.f, s_hn = 0.f;
        const f16* wr = bt2 + (size_t)col*2048 + 1024;
        const f16* wz = bt2 + (size_t)(1024+col)*2048 + 1024;
        const f16* wn = bt2 + (size_t)(2048+col)*2048 + 1024;
        for (int q = 0; q < 128; ++q){
          f16x8 hv = *reinterpret_cast<const f16x8*>(&hs[q*8]);
          f16x8 wrh = *reinterpret_cast<const f16x8*>(wr + q*8);
          f16x8 wzh = *reinterpret_cast<const f16x8*>(wz + q*8);
          f16x8 wnh = *reinterpret_cast<const f16x8*>(wn + q*8);
          #pragma unroll
          for (int e = 0; e < 8; ++e){
            float hh = (float)hv[e];
            s_r  += hh*(float)wrh[e];
            s_z  += hh*(float)wzh[e];
            s_hn += hh*(float)wnh[e];
          }
        }
        size_t rb = ((size_t)t*BB + b)*3072 + col;
        float r = 1.f / (1.f + expf(-((float)xi[rb] + s_r)));
        float z = 1.f / (1.f + expf(-((float)xi[rb + 1024] + s_z)));
        float nn = tanhf((float)xi[rb + 2048] + r * (s_hn + bhn_p[col]));
        float hold = (float)hs[col];
        float hnew = (1.f - z) * nn + z * hold;
        y[((size_t)t*BB + b)*HID + col] = (f16)hnew;
        if (t == TT - 1) hout[(size_t)b*HID + col] = hnew;
        tmp[u] = hnew;
      }
      __syncthreads();
      #pragma unroll
      for (int u = 0; u < 4; ++u) hs[tid*4 + u] = (f16)tmp[u];
      __syncthreads();
    }
    __syncthreads();
  }
}

// ---- critic: m97 + 2-phase dbuf (128x128, BK=64, 16 kt) + value fusion ----
__global__ __launch_bounds__(256)
void k_critic(const f16* __restrict__ Y, const f16* __restrict__ Bt,
              const float* __restrict__ b1, const float* __restrict__ W2,
              float* __restrict__ vpart){
  __shared__ __attribute__((aligned(16))) char smem[65536];
  int tid = threadIdx.x;
  int w = tid >> 6, lane = tid & 63;
  int wm = w >> 1, wn = w & 1;
  int bid = blockIdx.x;
  int vid = (bid & 7) * 128 + (bid >> 3);
  int Mb = (vid >> 3) * 128, Nb = (vid & 7) * 128;
  int la = lane & 15, lk = (lane >> 4) * 8;
  f32x4 acc[4][4] = {};
  int pr[4], pc16[4];
  #pragma unroll
  for (int q = 0; q < 4; ++q){
    int P = (w*4 + q)*1024 + lane*16;
    int r = P >> 7;
    pr[q] = r;
    pc16[q] = ((P & 127) ^ ((r & 7) << 4)) >> 4;
  }
  #pragma unroll
  for (int q = 0; q < 4; ++q){
    gload16(Y  + (size_t)(Mb + pr[q])*HID + pc16[q]*8, smem + (w*4 + q)*1024);
    gload16(Bt + (size_t)(Nb + pr[q])*HID + pc16[q]*8, smem + 16384 + (w*4 + q)*1024);
  }
  __syncthreads();
  for (int kt = 0; kt < 16; ++kt){
    const int cb = (kt & 1) * 32768;
    if (kt + 1 < 16){
      const int pb = ((kt + 1) & 1) * 32768;
      #pragma unroll
      for (int q = 0; q < 4; ++q){
        gload16(Y  + (size_t)(Mb + pr[q])*HID + (kt+1)*64 + pc16[q]*8,
                smem + pb + (w*4 + q)*1024);
        gload16(Bt + (size_t)(Nb + pr[q])*HID + (kt+1)*64 + pc16[q]*8,
                smem + pb + 16384 + (w*4 + q)*1024);
      }
    }
    #pragma unroll
    for (int kk = 0; kk < 64; kk += 32){
      f16x8 av[4], bv[4];
      #pragma unroll
      for (int m = 0; m < 4; ++m){
        int r = wm*64 + m*16 + la;
        av[m] = *reinterpret_cast<const f16x8*>(
            smem + cb + r*128 + (((kk + lk)*2) ^ ((r & 7) << 4)));
      }
      #pragma unroll
      for (int n = 0; n < 4; ++n){
        int r = wn*64 + n*16 + la;
        bv[n] = *reinterpret_cast<const f16x8*>(
            smem + cb + 16384 + r*128 + (((kk + lk)*2) ^ ((r & 7) << 4)));
      }
      #pragma unroll
      for (int m = 0; m < 4; ++m)
        #pragma unroll
        for (int n = 0; n < 4; ++n)
          acc[m][n] = mfma16(av[m], bv[n], acc[m][n]);
    }
    __syncthreads();
  }
  __shared__ float vs[2][64][2];
  float p[4][4];
  for (int mi = 0; mi < 4; ++mi) for (int i = 0; i < 4; ++i) p[mi][i] = 0.f;
  for (int ni = 0; ni < 4; ++ni){
    int col = Nb + wn*64 + ni*16 + la;
    float bb = b1[col], w2 = W2[col];
    for (int mi = 0; mi < 4; ++mi)
      for (int i = 0; i < 4; ++i){
        float c = acc[mi][ni][i] + bb;
        p[mi][i] += (c > 0.f ? c : 0.f) * w2;
      }
  }
  for (int mi = 0; mi < 4; ++mi) for (int i = 0; i < 4; ++i){
    float s = p[mi][i];
    s += __shfl_xor(s, 1); s += __shfl_xor(s, 2);
    s += __shfl_xor(s, 4); s += __shfl_xor(s, 8);
    p[mi][i] = s;
  }
  if (la == 0){
    int q = lane >> 4;
    for (int mi = 0; mi < 4; ++mi)
      for (int i = 0; i < 4; ++i)
        vs[wm][mi*16 + q*4 + i][wn] = p[mi][i];
  }
  __syncthreads();
  if (threadIdx.x < 128){
    int rw = threadIdx.x;
    float s = vs[rw >> 6][rw & 63][0] + vs[rw >> 6][rw & 63][1];
    vpart[(size_t)(Nb >> 7) * (TT*BB) + Mb + rw] = s;
  }
}

__global__ void k_vreduce(const float* __restrict__ vpart, const float* __restrict__ b2,
                          float* __restrict__ outv){
  int m = blockIdx.x * 256 + threadIdx.x;
  float s = b2[0];
  for (int nb = 0; nb < 8; ++nb) s += vpart[(size_t)nb * (TT*BB) + m];
  outv[m] = s;
}

extern "C" void kernel_launch(void* const* d_in, const int* in_sizes, int n_in,
                              void* d_out, int out_size, void* d_ws, size_t ws_size,
                              hipStream_t stream){
  const float* hidden = (const float*)d_in[0];
  const float* world  = (const float*)d_in[1];
  const int*   dones  = (const int*)d_in[2];
  const float* W_emb  = (const float*)d_in[3];
  const float* b_emb  = (const float*)d_in[4];
  const float* Wi     = (const float*)d_in[5];
  const float* bi     = (const float*)d_in[6];
  const float* Wh     = (const float*)d_in[7];
  const float* bhn    = (const float*)d_in[8];
  const float* W1     = (const float*)d_in[9];
  const float* b1     = (const float*)d_in[10];
  const float* W2     = (const float*)d_in[11];
  const float* b2     = (const float*)d_in[12];
  float* out = (float*)d_out;

  char* p = (char*)d_ws;
  auto alloc = [&](size_t bytes) -> char* {
    char* r = p; p += (bytes + 255) & ~(size_t)255; return r;
  };
  f16*   ws16   = (f16*)alloc((size_t)TT*BB*OBSD*2);     // 16 MB
  f16*   wembt  = (f16*)alloc((size_t)HID*OBSD*2);       // 1 MB
  f16*   emb16  = (f16*)alloc((size_t)TT*BB*HID*2);      // 33.5 MB
  f16*   bt2    = (f16*)alloc((size_t)3072*2048*2);      // 12.6 MB
  f16*   w1t    = (f16*)alloc((size_t)HID*HID*2);        // 2 MB
  f16*   xi16   = (f16*)alloc((size_t)TT*BB*3072*2);     // 100.7 MB
  f16*   ybuf   = (f16*)alloc((size_t)TT*BB*HID*2);      // 33.5 MB
  float* vpart  = (float*)alloc((size_t)8*TT*BB*4);      // 0.5 MB
  int*   cnt    = (int*)alloc(26*4);
  int*   rowlist= (int*)alloc((size_t)DPAR*BUCKCAP*4);   // 1.57 MB
  int*   zlist  = (int*)alloc((size_t)BUCKCAP*4);
  int*   chains = (int*)alloc((size_t)1024*3*4);
  if ((size_t)(p - (char*)d_ws) > ws_size) return;

  hipMemsetAsync(cnt, 0, 26*4, stream);

  // preps (+ segmentation, depends only on dones)
  k_ws_to_f16<<<(TT*BB*OBSD/4 + 255)/256, 256, 0, stream>>>(world, ws16, TT*BB*OBSD/4);
  k_prep_bt<<<dim3(OBSD/64, HID/64), 256, 0, stream>>>(W_emb, 1024, wembt, OBSD);
  k_prep_bt2<<<dim3(2048/64, 3072/64), 256, 0, stream>>>(Wi, Wh, bt2);
  k_prep_bt<<<dim3(HID/64, HID/64), 256, 0, stream>>>(W1, 1024, w1t, HID);
  k_seg<<<128, 128, 0, stream>>>(dones, cnt, rowlist, zlist, chains);

  // parallel GEMMs
  k_emb<<<1024, 256, 0, stream>>>(ws16, wembt, b_emb, emb16);
  k_xi<<<3072, 256, 0, stream>>>(emb16, bt2, bi, xi16);

  // h-zero rows (no GEMM) + depth-parallel GRU scan + tail
  k_h0<<<2048, 256, 0, stream>>>(cnt, zlist, xi16, bhn, ybuf, out);
  for (int j = 0; j < DPAR; ++j){
    if (j == 1 || j == 2)
      k_depth_med<<<1024, 512, 0, stream>>>(j, cnt, rowlist, xi16, bt2, bhn,
                                            hidden, ybuf, out);
    else
      k_depth<<<1024, 512, 0, stream>>>(j, cnt, rowlist, xi16, bt2, bhn,
                                        hidden, ybuf, out);
  }
  k_tail<<<128, 256, 0, stream>>>(cnt, chains, xi16, bt2, bhn, ybuf, out);

  // critic head + value
  k_critic<<<1024, 256, 0, stream>>>(ybuf, w1t, b1, W2, vpart);
  k_vreduce<<<TT*BB/256, 256, 0, stream>>>(vpart, b2, out + (size_t)BB*HID);
}

// Round 24
// 634.438 us; speedup vs baseline: 1.4198x; 1.4198x over previous
//
#include <hip/hip_runtime.h>
#include <stdint.h>

#define TT 128
#define BB 128
#define OBSD 512
#define HID 1024
#define DPAR 24
#define BUCKCAP 16384

typedef _Float16 f16;
typedef _Float16 f16x8 __attribute__((ext_vector_type(8)));
typedef _Float16 f16x4 __attribute__((ext_vector_type(4)));
typedef float f32x4 __attribute__((ext_vector_type(4)));

__device__ __forceinline__ f32x4 mfma16(f16x8 a, f16x8 b, f32x4 c){
  return __builtin_amdgcn_mfma_f32_16x16x32_f16(a, b, c, 0, 0, 0);
}
__device__ __forceinline__ void gload16(const void* g, void* l){
  __builtin_amdgcn_global_load_lds(
      (const __attribute__((address_space(1))) unsigned int*)g,
      (__attribute__((address_space(3))) unsigned int*)l, 16, 0, 0);
}

// ---- prep: world_state f32 -> f16 ----
__global__ void k_ws_to_f16(const float* __restrict__ src, f16* __restrict__ dst, int n4){
  int i = blockIdx.x * blockDim.x + threadIdx.x;
  if (i < n4){
    float4 v = *reinterpret_cast<const float4*>(src + (size_t)i * 4);
    dst[(size_t)i*4 + 0] = (f16)v.x; dst[(size_t)i*4 + 1] = (f16)v.y;
    dst[(size_t)i*4 + 2] = (f16)v.z; dst[(size_t)i*4 + 3] = (f16)v.w;
  }
}

// ---- prep: transpose f32 [KD][C] (row stride srcStride) -> f16 dst[C][KD] ----
__global__ void k_prep_bt(const float* __restrict__ s0, int srcStride,
                          f16* __restrict__ dst, int KD){
  __shared__ f16 sm[64][65];
  int k0 = blockIdx.x * 64, c0 = blockIdx.y * 64;
  for (int it = 0; it < 16; ++it){
    int idx = it * 256 + threadIdx.x;
    int kr = idx >> 6, cc = idx & 63;
    sm[kr][cc] = (f16)s0[(size_t)(k0 + kr) * srcStride + (c0 + cc)];
  }
  __syncthreads();
  for (int it = 0; it < 16; ++it){
    int idx = it * 256 + threadIdx.x;
    int cr = idx >> 6, kc = idx & 63;
    dst[(size_t)(c0 + cr) * KD + (k0 + kc)] = sm[kc][cr];
  }
}

// ---- prep: bt2[c][k] = k<1024 ? Wi[k][c] : Wh[k-1024][c]; c<3072, k<2048 ----
__global__ void k_prep_bt2(const float* __restrict__ wi, const float* __restrict__ wh,
                           f16* __restrict__ dst){
  __shared__ f16 sm[64][65];
  int k0 = blockIdx.x * 64, c0 = blockIdx.y * 64;
  const float* src = (k0 < 1024) ? wi : wh;
  int kb = (k0 < 1024) ? k0 : k0 - 1024;
  for (int it = 0; it < 16; ++it){
    int idx = it * 256 + threadIdx.x;
    int kr = idx >> 6, cc = idx & 63;
    sm[kr][cc] = (f16)src[(size_t)(kb + kr) * 3072 + (c0 + cc)];
  }
  __syncthreads();
  for (int it = 0; it < 16; ++it){
    int idx = it * 256 + threadIdx.x;
    int cr = idx >> 6, kc = idx & 63;
    dst[(size_t)(c0 + cr) * 2048 + (k0 + kc)] = sm[kc][cr];
  }
}

// ---- segmentation v6: (t,b)-parallel, O(1)/thread bit math, ballot ranks ----
__global__ void k_seg(const int* __restrict__ dones, int* __restrict__ cnt,
                      int* __restrict__ rowlist, int* __restrict__ zlist,
                      int* __restrict__ chains){
  __shared__ unsigned long long sm_m[2];
  __shared__ int cntw[2][26];
  __shared__ int lbase[26];
  const int b = blockIdx.x, t = threadIdx.x;
  const int wv = t >> 6, lane = t & 63;
  bool pred = (t >= 1) && (dones[t*BB + b] != 0);
  unsigned long long bal = __ballot(pred);
  if (lane == 0) sm_m[wv] = bal;
  __syncthreads();
  const unsigned long long m0 = sm_m[0], m1 = sm_m[1];
  const bool d0 = (dones[b] != 0);
  int s, e;
  if (t < 64){
    unsigned long long msk = (t == 63) ? ~0ull : ((1ull << (t+1)) - 1);
    unsigned long long lo = m0 & msk;
    s = lo ? 63 - __builtin_clzll(lo) : 0;
    unsigned long long rem = m0 & ~msk;
    if (rem) e = __builtin_ctzll(rem);
    else if (m1) e = 64 + __builtin_ctzll(m1);
    else e = TT;
  } else {
    int u = t - 64;
    unsigned long long msk = (u == 63) ? ~0ull : ((1ull << (u+1)) - 1);
    unsigned long long hi = m1 & msk;
    if (hi) s = 64 + 63 - __builtin_clzll(hi);
    else s = m0 ? 63 - __builtin_clzll(m0) : 0;
    unsigned long long rem = m1 & ~msk;
    e = rem ? 64 + __builtin_ctzll(rem) : TT;
  }
  const int d = t - s;
  int my_d;
  if (d == 0)            my_d = (s == 0 && !d0) ? 0 : 24;
  else if (d < DPAR)     my_d = d;
  else if (d == DPAR)    my_d = 25;
  else                   my_d = 26;
  int my_rank = 0;
  for (int d2 = 0; d2 < 26; ++d2){
    unsigned long long mk = __ballot(my_d == d2);
    if (my_d == d2) my_rank = __popcll(mk & ((1ull << lane) - 1));
    if (lane == 0) cntw[wv][d2] = __popcll(mk);
  }
  __syncthreads();
  if (wv == 1 && my_d < 26) my_rank += cntw[0][my_d];
  if (t < 26){
    int tot = cntw[0][t] + cntw[1][t];
    lbase[t] = tot ? atomicAdd(&cnt[t], tot) : 0;
  }
  __syncthreads();
  if (my_d < 24){
    rowlist[my_d*BUCKCAP + lbase[my_d] + my_rank] = (t << 7) | b;
  } else if (my_d == 24){
    zlist[lbase[24] + my_rank] = (t << 7) | b;
  } else if (my_d == 25){
    int c = lbase[25] + my_rank;
    chains[c*3+0] = b; chains[c*3+1] = s; chains[c*3+2] = e - s;
  }
}

// ---- emb = relu(ws @ W_emb + b_emb): m97 + 2-phase dbuf, K=512 (8 kt) ----
__global__ __launch_bounds__(256)
void k_emb(const f16* __restrict__ A, const f16* __restrict__ Bt,
           const float* __restrict__ bias, f16* __restrict__ outb){
  __shared__ __attribute__((aligned(16))) char smem[65536];
  int tid = threadIdx.x;
  int w = tid >> 6, lane = tid & 63;
  int wm = w >> 1, wn = w & 1;
  int bid = blockIdx.x;                       // 1024 = 128 Mb x 8 Nb
  int vid = (bid & 7) * 128 + (bid >> 3);
  int Mb = (vid >> 3) * 128, Nb = (vid & 7) * 128;
  int la = lane & 15, lk = (lane >> 4) * 8;
  f32x4 acc[4][4] = {};
  int pr[4], pc16[4];
  #pragma unroll
  for (int q = 0; q < 4; ++q){
    int P = (w*4 + q)*1024 + lane*16;
    int r = P >> 7;
    pr[q] = r;
    pc16[q] = ((P & 127) ^ ((r & 7) << 4)) >> 4;
  }
  #pragma unroll
  for (int q = 0; q < 4; ++q){
    gload16(A  + (size_t)(Mb + pr[q])*OBSD + pc16[q]*8, smem + (w*4 + q)*1024);
    gload16(Bt + (size_t)(Nb + pr[q])*OBSD + pc16[q]*8, smem + 16384 + (w*4 + q)*1024);
  }
  __syncthreads();
  for (int kt = 0; kt < 8; ++kt){
    const int cb = (kt & 1) * 32768;
    if (kt + 1 < 8){
      const int pb = ((kt + 1) & 1) * 32768;
      #pragma unroll
      for (int q = 0; q < 4; ++q){
        gload16(A  + (size_t)(Mb + pr[q])*OBSD + (kt+1)*64 + pc16[q]*8,
                smem + pb + (w*4 + q)*1024);
        gload16(Bt + (size_t)(Nb + pr[q])*OBSD + (kt+1)*64 + pc16[q]*8,
                smem + pb + 16384 + (w*4 + q)*1024);
      }
    }
    #pragma unroll
    for (int kk = 0; kk < 64; kk += 32){
      f16x8 av[4], bv[4];
      #pragma unroll
      for (int m = 0; m < 4; ++m){
        int r = wm*64 + m*16 + la;
        av[m] = *reinterpret_cast<const f16x8*>(
            smem + cb + r*128 + (((kk + lk)*2) ^ ((r & 7) << 4)));
      }
      #pragma unroll
      for (int n = 0; n < 4; ++n){
        int r = wn*64 + n*16 + la;
        bv[n] = *reinterpret_cast<const f16x8*>(
            smem + cb + 16384 + r*128 + (((kk + lk)*2) ^ ((r & 7) << 4)));
      }
      #pragma unroll
      for (int m = 0; m < 4; ++m)
        #pragma unroll
        for (int n = 0; n < 4; ++n)
          acc[m][n] = mfma16(av[m], bv[n], acc[m][n]);
    }
    __syncthreads();
  }
  for (int mi = 0; mi < 4; ++mi) for (int ni = 0; ni < 4; ++ni){
    int col = Nb + wn*64 + ni*16 + la;
    float bb = bias[col];
    for (int i = 0; i < 4; ++i){
      int row = Mb + wm*64 + mi*16 + (lane >> 4)*4 + i;
      float v = acc[mi][ni][i] + bb;
      outb[(size_t)row * HID + col] = (f16)(v > 0.f ? v : 0.f);
    }
  }
}

// ---- xi = emb @ Wi + bi: m97 + 2-phase dbuf (128x128, BK=64, 16 kt) ----
__global__ __launch_bounds__(256)
void k_xi(const f16* __restrict__ A, const f16* __restrict__ Bt,
          const float* __restrict__ bias, f16* __restrict__ outb){
  __shared__ __attribute__((aligned(16))) char smem[65536];
  int tid = threadIdx.x;
  int w = tid >> 6, lane = tid & 63;
  int wm = w >> 1, wn = w & 1;
  int bid = blockIdx.x;                       // 3072 = 128 Mb x 24 Nb
  int vid = (bid & 7) * 384 + (bid >> 3);
  int Mb = (vid / 24) * 128, Nb = (vid % 24) * 128;
  int la = lane & 15, lk = (lane >> 4) * 8;
  f32x4 acc[4][4] = {};
  int pr[4], pc16[4];
  #pragma unroll
  for (int q = 0; q < 4; ++q){
    int P = (w*4 + q)*1024 + lane*16;
    int r = P >> 7;
    pr[q] = r;
    pc16[q] = ((P & 127) ^ ((r & 7) << 4)) >> 4;
  }
  #pragma unroll
  for (int q = 0; q < 4; ++q){
    gload16(A  + (size_t)(Mb + pr[q])*HID  + pc16[q]*8, smem + (w*4 + q)*1024);
    gload16(Bt + (size_t)(Nb + pr[q])*2048 + pc16[q]*8, smem + 16384 + (w*4 + q)*1024);
  }
  __syncthreads();
  for (int kt = 0; kt < 16; ++kt){
    const int cb = (kt & 1) * 32768;
    if (kt + 1 < 16){
      const int pb = ((kt + 1) & 1) * 32768;
      #pragma unroll
      for (int q = 0; q < 4; ++q){
        gload16(A  + (size_t)(Mb + pr[q])*HID  + (kt+1)*64 + pc16[q]*8,
                smem + pb + (w*4 + q)*1024);
        gload16(Bt + (size_t)(Nb + pr[q])*2048 + (kt+1)*64 + pc16[q]*8,
                smem + pb + 16384 + (w*4 + q)*1024);
      }
    }
    #pragma unroll
    for (int kk = 0; kk < 64; kk += 32){
      f16x8 av[4], bv[4];
      #pragma unroll
      for (int m = 0; m < 4; ++m){
        int r = wm*64 + m*16 + la;
        av[m] = *reinterpret_cast<const f16x8*>(
            smem + cb + r*128 + (((kk + lk)*2) ^ ((r & 7) << 4)));
      }
      #pragma unroll
      for (int n = 0; n < 4; ++n){
        int r = wn*64 + n*16 + la;
        bv[n] = *reinterpret_cast<const f16x8*>(
            smem + cb + 16384 + r*128 + (((kk + lk)*2) ^ ((r & 7) << 4)));
      }
      #pragma unroll
      for (int m = 0; m < 4; ++m)
        #pragma unroll
        for (int n = 0; n < 4; ++n)
          acc[m][n] = mfma16(av[m], bv[n], acc[m][n]);
    }
    __syncthreads();
  }
  for (int mi = 0; mi < 4; ++mi) for (int ni = 0; ni < 4; ++ni){
    int col = Nb + wn*64 + ni*16 + la;
    float bb = bias[col];
    for (int i = 0; i < 4; ++i){
      int row = Mb + wm*64 + mi*16 + (lane >> 4)*4 + i;
      outb[(size_t)row * 3072 + col] = (f16)(acc[mi][ni][i] + bb);
    }
  }
}

// ---- h-zero rows: h = (1-z)*n, straight from xi (no GEMM) ----
__global__ __launch_bounds__(256)
void k_h0(const int* __restrict__ cnt, const int* __restrict__ zlist,
          const f16* __restrict__ xi, const float* __restrict__ bhn_p,
          f16* __restrict__ y, float* __restrict__ hout){
  int nz = cnt[24];
  int tid = threadIdx.x;
  for (int ridx = blockIdx.x; ridx < nz; ridx += gridDim.x){
    int tb = zlist[ridx];
    int t = tb >> 7, b = tb & 127;
    size_t rb = ((size_t)t*BB + b) * 3072;
    int c0 = tid * 4;
    f16x4 xr = *reinterpret_cast<const f16x4*>(xi + rb + c0);
    f16x4 xz = *reinterpret_cast<const f16x4*>(xi + rb + 1024 + c0);
    f16x4 xn = *reinterpret_cast<const f16x4*>(xi + rb + 2048 + c0);
    f16x4 o;
    #pragma unroll
    for (int u = 0; u < 4; ++u){
      float r = 1.f / (1.f + expf(-(float)xr[u]));
      float z = 1.f / (1.f + expf(-(float)xz[u]));
      float n = tanhf((float)xn[u] + r * bhn_p[c0 + u]);
      float h = (1.f - z) * n;
      o[u] = (f16)h;
      if (t == TT - 1) hout[(size_t)b*HID + c0 + u] = h;
    }
    *reinterpret_cast<f16x4*>(y + ((size_t)t*BB + b)*HID + c0) = o;
  }
}

// ---- depth (small; used for j=0 and j>=3): 16 rows x 32 hcols/block ----
__global__ __launch_bounds__(512)
void k_depth(int j, const int* __restrict__ cnt, const int* __restrict__ rowlist_g,
             const f16* __restrict__ xi, const f16* __restrict__ bt2,
             const float* __restrict__ bhn_p, const float* __restrict__ hidden0,
             f16* __restrict__ y, float* __restrict__ hout){
  __shared__ __attribute__((aligned(16))) char smem[32768];
  const int count = cnt[j];
  if (count <= 0) return;
  const int* rowlist = rowlist_g + (size_t)j * BUCKCAP;
  const int tid = threadIdx.x;
  const int lane = tid & 63;
  const int w = tid >> 6;
  const int bid = blockIdx.x;
  const int la = lane & 15, lk = (lane >> 4) * 8;
  float* red = (float*)smem;
  const int vid = (bid & 7) * 128 + (bid >> 3);
  const int cs2 = vid >> 5;
  const int rgs = vid & 31;
  const int cg = w >> 2, kq = w & 3;
  const f16* Bq0 = bt2 + (size_t)(          cs2*32 + cg*16 + la)*2048 + 1024 + kq*256 + lk;
  const f16* Bq1 = bt2 + (size_t)(1024 +    cs2*32 + cg*16 + la)*2048 + 1024 + kq*256 + lk;
  const f16* Bq2 = bt2 + (size_t)(2048 +    cs2*32 + cg*16 + la)*2048 + 1024 + kq*256 + lk;
  const int es = tid >> 8, ei = (tid >> 6) & 3, elane = tid & 63;
  const int erow_l = ((elane >> 4) << 2) + ei;
  const int ecol = cs2*32 + es*16 + (elane & 15);
  const float bh = bhn_p[ecol];
  const int nrg = (count + 15) >> 4;
  for (int rg = rgs; rg < nrg; rg += 32){
    __syncthreads();
    #pragma unroll
    for (int it = 0; it < 4; ++it){
      int idx = tid + it*512;
      int r = idx >> 7, part = idx & 127;
      int ridx = rg*16 + r;
      int tb = (ridx < count) ? rowlist[ridx] : -1;
      float4 v = {0.f, 0.f, 0.f, 0.f};
      if (tb >= 0){
        int t = tb >> 7, bb_ = tb & 127;
        if (j > 0){
          v = *reinterpret_cast<const float4*>(y + ((size_t)(t-1)*BB + bb_)*HID + part*8);
        } else {
          const float* s = hidden0 + (size_t)bb_*HID + part*8;
          float4 a0 = *reinterpret_cast<const float4*>(s);
          float4 a1 = *reinterpret_cast<const float4*>(s + 4);
          f16 h8[8] = {(f16)a0.x,(f16)a0.y,(f16)a0.z,(f16)a0.w,
                       (f16)a1.x,(f16)a1.y,(f16)a1.z,(f16)a1.w};
          v = *reinterpret_cast<float4*>(h8);
        }
      }
      *reinterpret_cast<float4*>(smem + ((r*2048 + part*16) ^ ((r & 7) << 4))) = v;
    }
    __syncthreads();
    f32x4 a0 = {}, a1 = {}, a2 = {};
    #pragma unroll
    for (int kk = 0; kk < 256; kk += 32){
      int k = kq*256 + kk + lk;
      f16x8 av = *reinterpret_cast<const f16x8*>(
          smem + ((la*2048 + k*2) ^ ((la & 7) << 4)));
      a0 = mfma16(av, *reinterpret_cast<const f16x8*>(Bq0 + kk), a0);
      a1 = mfma16(av, *reinterpret_cast<const f16x8*>(Bq1 + kk), a1);
      a2 = mfma16(av, *reinterpret_cast<const f16x8*>(Bq2 + kk), a2);
    }
    __syncthreads();
    #pragma unroll
    for (int i = 0; i < 4; ++i){
      red[((((cg*4 + kq)*3 + 0)*64 + lane)*5) + i] = a0[i];
      red[((((cg*4 + kq)*3 + 1)*64 + lane)*5) + i] = a1[i];
      red[((((cg*4 + kq)*3 + 2)*64 + lane)*5) + i] = a2[i];
    }
    __syncthreads();
    int ridx = rg*16 + erow_l;
    if (ridx < count){
      int tb = rowlist[ridx];
      int t = tb >> 7, bb_ = tb & 127;
      float hr = 0.f, hz = 0.f, hn = 0.f;
      #pragma unroll
      for (int kq2 = 0; kq2 < 4; ++kq2){
        hr += red[((((es*4 + kq2)*3 + 0)*64 + elane)*5) + ei];
        hz += red[((((es*4 + kq2)*3 + 1)*64 + elane)*5) + ei];
        hn += red[((((es*4 + kq2)*3 + 2)*64 + elane)*5) + ei];
      }
      size_t rb = ((size_t)t*BB + bb_)*3072 + ecol;
      float hold;
      if (j > 0) hold = (float)y[((size_t)(t-1)*BB + bb_)*HID + ecol];
      else       hold = hidden0[(size_t)bb_*HID + ecol];
      float r = 1.f / (1.f + expf(-((float)xi[rb]        + hr)));
      float z = 1.f / (1.f + expf(-((float)xi[rb + 1024] + hz)));
      float n = tanhf((float)xi[rb + 2048] + r * (hn + bh));
      float hnew = (1.f - z) * n + z * hold;
      y[((size_t)t*BB + bb_)*HID + ecol] = (f16)hnew;
      if (t == TT - 1) hout[(size_t)bb_*HID + ecol] = hnew;
    }
  }
}

// ---- depth GEMM (j=1,2): hh[ridx][3072] = h_prev @ Wh; m97 template,
// gathered A rows (per-lane global src for gload16), rows>=count clamped ----
__global__ __launch_bounds__(256)
void k_depth_gemm(int j, const int* __restrict__ cnt, const int* __restrict__ rowlist_g,
                  const f16* __restrict__ y, const f16* __restrict__ bt2,
                  f16* __restrict__ hh){
  __shared__ __attribute__((aligned(16))) char smem[65536];
  const int count = cnt[j];
  if (count <= 0) return;
  const int* rowlist = rowlist_g + (size_t)j * BUCKCAP;
  int tid = threadIdx.x;
  int w = tid >> 6, lane = tid & 63;
  int wm = w >> 1, wn = w & 1;
  int bid = blockIdx.x;                       // 1536 = 64 Mt x 24 Nb
  int vid = (bid & 7) * 192 + (bid >> 3);
  int Mb = (vid / 24) * 128, Nb = (vid % 24) * 128;
  if (Mb >= count) return;
  int la = lane & 15, lk = (lane >> 4) * 8;
  f32x4 acc[4][4] = {};
  int pr[4], pc16[4];
  const f16* rp[4];
  #pragma unroll
  for (int q = 0; q < 4; ++q){
    int P = (w*4 + q)*1024 + lane*16;
    int r = P >> 7;
    pr[q] = r;
    pc16[q] = ((P & 127) ^ ((r & 7) << 4)) >> 4;
    int ridx = Mb + r; if (ridx >= count) ridx = count - 1;
    int tb = rowlist[ridx];
    rp[q] = y + ((size_t)((tb >> 7) - 1)*BB + (tb & 127))*HID;
  }
  #pragma unroll
  for (int q = 0; q < 4; ++q){
    gload16(rp[q] + pc16[q]*8, smem + (w*4 + q)*1024);
    gload16(bt2 + (size_t)(Nb + pr[q])*2048 + 1024 + pc16[q]*8,
            smem + 16384 + (w*4 + q)*1024);
  }
  __syncthreads();
  for (int kt = 0; kt < 16; ++kt){
    const int cb = (kt & 1) * 32768;
    if (kt + 1 < 16){
      const int pb = ((kt + 1) & 1) * 32768;
      #pragma unroll
      for (int q = 0; q < 4; ++q){
        gload16(rp[q] + (kt+1)*64 + pc16[q]*8, smem + pb + (w*4 + q)*1024);
        gload16(bt2 + (size_t)(Nb + pr[q])*2048 + 1024 + (kt+1)*64 + pc16[q]*8,
                smem + pb + 16384 + (w*4 + q)*1024);
      }
    }
    #pragma unroll
    for (int kk = 0; kk < 64; kk += 32){
      f16x8 av[4], bv[4];
      #pragma unroll
      for (int m = 0; m < 4; ++m){
        int r = wm*64 + m*16 + la;
        av[m] = *reinterpret_cast<const f16x8*>(
            smem + cb + r*128 + (((kk + lk)*2) ^ ((r & 7) << 4)));
      }
      #pragma unroll
      for (int n = 0; n < 4; ++n){
        int r = wn*64 + n*16 + la;
        bv[n] = *reinterpret_cast<const f16x8*>(
            smem + cb + 16384 + r*128 + (((kk + lk)*2) ^ ((r & 7) << 4)));
      }
      #pragma unroll
      for (int m = 0; m < 4; ++m)
        #pragma unroll
        for (int n = 0; n < 4; ++n)
          acc[m][n] = mfma16(av[m], bv[n], acc[m][n]);
    }
    __syncthreads();
  }
  for (int mi = 0; mi < 4; ++mi) for (int ni = 0; ni < 4; ++ni){
    int col = Nb + wn*64 + ni*16 + la;
    for (int i = 0; i < 4; ++i){
      int row = Mb + wm*64 + mi*16 + (lane >> 4)*4 + i;
      hh[(size_t)row * 3072 + col] = (f16)acc[mi][ni][i];
    }
  }
}

// ---- depth epilogue (j=1,2): gates from xi + hh, write y[t] ----
__global__ __launch_bounds__(256)
void k_depth_ep(int j, const int* __restrict__ cnt, const int* __restrict__ rowlist_g,
                const f16* __restrict__ hh, const f16* __restrict__ xi,
                const float* __restrict__ bhn_p, f16* __restrict__ y,
                float* __restrict__ hout){
  const int count = cnt[j];
  const int* rowlist = rowlist_g + (size_t)j * BUCKCAP;
  int tid = threadIdx.x;
  int c0 = tid * 4;
  for (int ridx = blockIdx.x; ridx < count; ridx += gridDim.x){
    int tb = rowlist[ridx];
    int t = tb >> 7, b = tb & 127;
    size_t hb = (size_t)ridx * 3072;
    f16x4 hr4 = *reinterpret_cast<const f16x4*>(hh + hb + c0);
    f16x4 hz4 = *reinterpret_cast<const f16x4*>(hh + hb + 1024 + c0);
    f16x4 hn4 = *reinterpret_cast<const f16x4*>(hh + hb + 2048 + c0);
    size_t rb = ((size_t)t*BB + b)*3072 + c0;
    f16x4 xr4 = *reinterpret_cast<const f16x4*>(xi + rb);
    f16x4 xz4 = *reinterpret_cast<const f16x4*>(xi + rb + 1024);
    f16x4 xn4 = *reinterpret_cast<const f16x4*>(xi + rb + 2048);
    f16x4 ho4 = *reinterpret_cast<const f16x4*>(y + ((size_t)(t-1)*BB + b)*HID + c0);
    f16x4 o;
    #pragma unroll
    for (int u = 0; u < 4; ++u){
      float r = 1.f / (1.f + expf(-((float)xr4[u] + (float)hr4[u])));
      float z = 1.f / (1.f + expf(-((float)xz4[u] + (float)hz4[u])));
      float n = tanhf((float)xn4[u] + r * ((float)hn4[u] + bhn_p[c0 + u]));
      float hnew = (1.f - z) * n + z * (float)ho4[u];
      o[u] = (f16)hnew;
      if (t == TT - 1) hout[(size_t)b*HID + c0 + u] = hnew;
    }
    *reinterpret_cast<f16x4*>(y + ((size_t)t*BB + b)*HID + c0) = o;
  }
}

// ---- sequential tail for chains longer than DPAR (empty for this seed) ----
__global__ __launch_bounds__(256)
void k_tail(const int* __restrict__ cnt, const int* __restrict__ chains,
            const f16* __restrict__ xi, const f16* __restrict__ bt2,
            const float* __restrict__ bhn_p, f16* __restrict__ y,
            float* __restrict__ hout){
  int n = cnt[25];
  __shared__ f16 hs[1024];
  int tid = threadIdx.x;
  for (int c = blockIdx.x; c < n; c += gridDim.x){
    int b = chains[c*3], t0 = chains[c*3+1], len = chains[c*3+2];
    for (int i = tid; i < 1024; i += 256)
      hs[i] = y[((size_t)(t0 + DPAR - 1)*BB + b)*HID + i];
    __syncthreads();
    for (int t = t0 + DPAR; t < t0 + len; ++t){
      float tmp[4];
      #pragma unroll
      for (int u = 0; u < 4; ++u){
        int col = tid*4 + u;
        float s_r = 0.f, s_z = 0.f, s_hn = 0.f;
        const f16* wr = bt2 + (size_t)col*2048 + 1024;
        const f16* wz = bt2 + (size_t)(1024+col)*2048 + 1024;
        const f16* wn = bt2 + (size_t)(2048+col)*2048 + 1024;
        for (int q = 0; q < 128; ++q){
          f16x8 hv = *reinterpret_cast<const f16x8*>(&hs[q*8]);
          f16x8 wrh = *reinterpret_cast<const f16x8*>(wr + q*8);
          f16x8 wzh = *reinterpret_cast<const f16x8*>(wz + q*8);
          f16x8 wnh = *reinterpret_cast<const f16x8*>(wn + q*8);
          #pragma unroll
          for (int e = 0; e < 8; ++e){
            float hh_ = (float)hv[e];
            s_r  += hh_*(float)wrh[e];
            s_z  += hh_*(float)wzh[e];
            s_hn += hh_*(float)wnh[e];
          }
        }
        size_t rb = ((size_t)t*BB + b)*3072 + col;
        float r = 1.f / (1.f + expf(-((float)xi[rb] + s_r)));
        float z = 1.f / (1.f + expf(-((float)xi[rb + 1024] + s_z)));
        float nn = tanhf((float)xi[rb + 2048] + r * (s_hn + bhn_p[col]));
        float hold = (float)hs[col];
        float hnew = (1.f - z) * nn + z * hold;
        y[((size_t)t*BB + b)*HID + col] = (f16)hnew;
        if (t == TT - 1) hout[(size_t)b*HID + col] = hnew;
        tmp[u] = hnew;
      }
      __syncthreads();
      #pragma unroll
      for (int u = 0; u < 4; ++u) hs[tid*4 + u] = (f16)tmp[u];
      __syncthreads();
    }
    __syncthreads();
  }
}

// ---- critic: m97 + 2-phase dbuf (128x128, BK=64, 16 kt) + value fusion ----
__global__ __launch_bounds__(256)
void k_critic(const f16* __restrict__ Y, const f16* __restrict__ Bt,
              const float* __restrict__ b1, const float* __restrict__ W2,
              float* __restrict__ vpart){
  __shared__ __attribute__((aligned(16))) char smem[65536];
  int tid = threadIdx.x;
  int w = tid >> 6, lane = tid & 63;
  int wm = w >> 1, wn = w & 1;
  int bid = blockIdx.x;
  int vid = (bid & 7) * 128 + (bid >> 3);
  int Mb = (vid >> 3) * 128, Nb = (vid & 7) * 128;
  int la = lane & 15, lk = (lane >> 4) * 8;
  f32x4 acc[4][4] = {};
  int pr[4], pc16[4];
  #pragma unroll
  for (int q = 0; q < 4; ++q){
    int P = (w*4 + q)*1024 + lane*16;
    int r = P >> 7;
    pr[q] = r;
    pc16[q] = ((P & 127) ^ ((r & 7) << 4)) >> 4;
  }
  #pragma unroll
  for (int q = 0; q < 4; ++q){
    gload16(Y  + (size_t)(Mb + pr[q])*HID + pc16[q]*8, smem + (w*4 + q)*1024);
    gload16(Bt + (size_t)(Nb + pr[q])*HID + pc16[q]*8, smem + 16384 + (w*4 + q)*1024);
  }
  __syncthreads();
  for (int kt = 0; kt < 16; ++kt){
    const int cb = (kt & 1) * 32768;
    if (kt + 1 < 16){
      const int pb = ((kt + 1) & 1) * 32768;
      #pragma unroll
      for (int q = 0; q < 4; ++q){
        gload16(Y  + (size_t)(Mb + pr[q])*HID + (kt+1)*64 + pc16[q]*8,
                smem + pb + (w*4 + q)*1024);
        gload16(Bt + (size_t)(Nb + pr[q])*HID + (kt+1)*64 + pc16[q]*8,
                smem + pb + 16384 + (w*4 + q)*1024);
      }
    }
    #pragma unroll
    for (int kk = 0; kk < 64; kk += 32){
      f16x8 av[4], bv[4];
      #pragma unroll
      for (int m = 0; m < 4; ++m){
        int r = wm*64 + m*16 + la;
        av[m] = *reinterpret_cast<const f16x8*>(
            smem + cb + r*128 + (((kk + lk)*2) ^ ((r & 7) << 4)));
      }
      #pragma unroll
      for (int n = 0; n < 4; ++n){
        int r = wn*64 + n*16 + la;
        bv[n] = *reinterpret_cast<const f16x8*>(
            smem + cb + 16384 + r*128 + (((kk + lk)*2) ^ ((r & 7) << 4)));
      }
      #pragma unroll
      for (int m = 0; m < 4; ++m)
        #pragma unroll
        for (int n = 0; n < 4; ++n)
          acc[m][n] = mfma16(av[m], bv[n], acc[m][n]);
    }
    __syncthreads();
  }
  __shared__ float vs[2][64][2];
  float p[4][4];
  for (int mi = 0; mi < 4; ++mi) for (int i = 0; i < 4; ++i) p[mi][i] = 0.f;
  for (int ni = 0; ni < 4; ++ni){
    int col = Nb + wn*64 + ni*16 + la;
    float bb = b1[col], w2 = W2[col];
    for (int mi = 0; mi < 4; ++mi)
      for (int i = 0; i < 4; ++i){
        float c = acc[mi][ni][i] + bb;
        p[mi][i] += (c > 0.f ? c : 0.f) * w2;
      }
  }
  for (int mi = 0; mi < 4; ++mi) for (int i = 0; i < 4; ++i){
    float s = p[mi][i];
    s += __shfl_xor(s, 1); s += __shfl_xor(s, 2);
    s += __shfl_xor(s, 4); s += __shfl_xor(s, 8);
    p[mi][i] = s;
  }
  if (la == 0){
    int q = lane >> 4;
    for (int mi = 0; mi < 4; ++mi)
      for (int i = 0; i < 4; ++i)
        vs[wm][mi*16 + q*4 + i][wn] = p[mi][i];
  }
  __syncthreads();
  if (threadIdx.x < 128){
    int rw = threadIdx.x;
    float s = vs[rw >> 6][rw & 63][0] + vs[rw >> 6][rw & 63][1];
    vpart[(size_t)(Nb >> 7) * (TT*BB) + Mb + rw] = s;
  }
}

__global__ void k_vreduce(const float* __restrict__ vpart, const float* __restrict__ b2,
                          float* __restrict__ outv){
  int m = blockIdx.x * 256 + threadIdx.x;
  float s = b2[0];
  for (int nb = 0; nb < 8; ++nb) s += vpart[(size_t)nb * (TT*BB) + m];
  outv[m] = s;
}

extern "C" void kernel_launch(void* const* d_in, const int* in_sizes, int n_in,
                              void* d_out, int out_size, void* d_ws, size_t ws_size,
                              hipStream_t stream){
  const float* hidden = (const float*)d_in[0];
  const float* world  = (const float*)d_in[1];
  const int*   dones  = (const int*)d_in[2];
  const float* W_emb  = (const float*)d_in[3];
  const float* b_emb  = (const float*)d_in[4];
  const float* Wi     = (const float*)d_in[5];
  const float* bi     = (const float*)d_in[6];
  const float* Wh     = (const float*)d_in[7];
  const float* bhn    = (const float*)d_in[8];
  const float* W1     = (const float*)d_in[9];
  const float* b1     = (const float*)d_in[10];
  const float* W2     = (const float*)d_in[11];
  const float* b2     = (const float*)d_in[12];
  float* out = (float*)d_out;

  char* p = (char*)d_ws;
  auto alloc = [&](size_t bytes) -> char* {
    char* r = p; p += (bytes + 255) & ~(size_t)255; return r;
  };
  f16*   ws16   = (f16*)alloc((size_t)TT*BB*OBSD*2);     // 16 MB   } hh (50.3 MB)
  f16*   wembt  = (f16*)alloc((size_t)HID*OBSD*2);       // 1 MB    } overlays these
  f16*   emb16  = (f16*)alloc((size_t)TT*BB*HID*2);      // 33.5 MB } (dead post-k_xi)
  f16*   bt2    = (f16*)alloc((size_t)3072*2048*2);      // 12.6 MB
  f16*   w1t    = (f16*)alloc((size_t)HID*HID*2);        // 2 MB
  f16*   xi16   = (f16*)alloc((size_t)TT*BB*3072*2);     // 100.7 MB
  f16*   ybuf   = (f16*)alloc((size_t)TT*BB*HID*2);      // 33.5 MB
  float* vpart  = (float*)alloc((size_t)8*TT*BB*4);      // 0.5 MB
  int*   cnt    = (int*)alloc(26*4);
  int*   rowlist= (int*)alloc((size_t)DPAR*BUCKCAP*4);   // 1.57 MB
  int*   zlist  = (int*)alloc((size_t)BUCKCAP*4);
  int*   chains = (int*)alloc((size_t)1024*3*4);
  if ((size_t)(p - (char*)d_ws) > ws_size) return;
  f16* hh = (f16*)d_ws;   // 8192 x 3072 f16 = 50.3 MB, overlays ws16..emb16

  hipMemsetAsync(cnt, 0, 26*4, stream);

  // preps (+ segmentation, depends only on dones)
  k_ws_to_f16<<<(TT*BB*OBSD/4 + 255)/256, 256, 0, stream>>>(world, ws16, TT*BB*OBSD/4);
  k_prep_bt<<<dim3(OBSD/64, HID/64), 256, 0, stream>>>(W_emb, 1024, wembt, OBSD);
  k_prep_bt2<<<dim3(2048/64, 3072/64), 256, 0, stream>>>(Wi, Wh, bt2);
  k_prep_bt<<<dim3(HID/64, HID/64), 256, 0, stream>>>(W1, 1024, w1t, HID);
  k_seg<<<128, 128, 0, stream>>>(dones, cnt, rowlist, zlist, chains);

  // parallel GEMMs
  k_emb<<<1024, 256, 0, stream>>>(ws16, wembt, b_emb, emb16);
  k_xi<<<3072, 256, 0, stream>>>(emb16, bt2, bi, xi16);

  // h-zero rows (no GEMM) + depth-parallel GRU scan + tail
  k_h0<<<2048, 256, 0, stream>>>(cnt, zlist, xi16, bhn, ybuf, out);
  for (int j = 0; j < DPAR; ++j){
    if (j == 1 || j == 2){
      k_depth_gemm<<<1536, 256, 0, stream>>>(j, cnt, rowlist, ybuf, bt2, hh);
      k_depth_ep<<<2048, 256, 0, stream>>>(j, cnt, rowlist, hh, xi16, bhn, ybuf, out);
    } else {
      k_depth<<<1024, 512, 0, stream>>>(j, cnt, rowlist, xi16, bt2, bhn,
                                        hidden, ybuf, out);
    }
  }
  k_tail<<<128, 256, 0, stream>>>(cnt, chains, xi16, bt2, bhn, ybuf, out);

  // critic head + value
  k_critic<<<1024, 256, 0, stream>>>(ybuf, w1t, b1, W2, vpart);
  k_vreduce<<<TT*BB/256, 256, 0, stream>>>(vpart, b2, out + (size_t)BB*HID);
}

// Round 25
// 564.358 us; speedup vs baseline: 1.5961x; 1.1242x over previous
//
#include <hip/hip_runtime.h>
#include <stdint.h>

#define TT 128
#define BB 128
#define OBSD 512
#define HID 1024
#define DPAR 24
#define BUCKCAP 16384

typedef _Float16 f16;
typedef _Float16 f16x8 __attribute__((ext_vector_type(8)));
typedef _Float16 f16x4 __attribute__((ext_vector_type(4)));
typedef float f32x4 __attribute__((ext_vector_type(4)));

__device__ __forceinline__ f32x4 mfma16(f16x8 a, f16x8 b, f32x4 c){
  return __builtin_amdgcn_mfma_f32_16x16x32_f16(a, b, c, 0, 0, 0);
}
__device__ __forceinline__ void gload16(const void* g, void* l){
  __builtin_amdgcn_global_load_lds(
      (const __attribute__((address_space(1))) unsigned int*)g,
      (__attribute__((address_space(3))) unsigned int*)l, 16, 0, 0);
}

// ---- prep: world_state f32 -> f16 ----
__global__ void k_ws_to_f16(const float* __restrict__ src, f16* __restrict__ dst, int n4){
  int i = blockIdx.x * blockDim.x + threadIdx.x;
  if (i < n4){
    float4 v = *reinterpret_cast<const float4*>(src + (size_t)i * 4);
    dst[(size_t)i*4 + 0] = (f16)v.x; dst[(size_t)i*4 + 1] = (f16)v.y;
    dst[(size_t)i*4 + 2] = (f16)v.z; dst[(size_t)i*4 + 3] = (f16)v.w;
  }
}

// ---- prep: transpose f32 [KD][C] (row stride srcStride) -> f16 dst[C][KD] ----
__global__ void k_prep_bt(const float* __restrict__ s0, int srcStride,
                          f16* __restrict__ dst, int KD){
  __shared__ f16 sm[64][65];
  int k0 = blockIdx.x * 64, c0 = blockIdx.y * 64;
  for (int it = 0; it < 16; ++it){
    int idx = it * 256 + threadIdx.x;
    int kr = idx >> 6, cc = idx & 63;
    sm[kr][cc] = (f16)s0[(size_t)(k0 + kr) * srcStride + (c0 + cc)];
  }
  __syncthreads();
  for (int it = 0; it < 16; ++it){
    int idx = it * 256 + threadIdx.x;
    int cr = idx >> 6, kc = idx & 63;
    dst[(size_t)(c0 + cr) * KD + (k0 + kc)] = sm[kc][cr];
  }
}

// ---- prep: bt2[c][k] = k<1024 ? Wi[k][c] : Wh[k-1024][c]; c<3072, k<2048 ----
__global__ void k_prep_bt2(const float* __restrict__ wi, const float* __restrict__ wh,
                           f16* __restrict__ dst){
  __shared__ f16 sm[64][65];
  int k0 = blockIdx.x * 64, c0 = blockIdx.y * 64;
  const float* src = (k0 < 1024) ? wi : wh;
  int kb = (k0 < 1024) ? k0 : k0 - 1024;
  for (int it = 0; it < 16; ++it){
    int idx = it * 256 + threadIdx.x;
    int kr = idx >> 6, cc = idx & 63;
    sm[kr][cc] = (f16)src[(size_t)(kb + kr) * 3072 + (c0 + cc)];
  }
  __syncthreads();
  for (int it = 0; it < 16; ++it){
    int idx = it * 256 + threadIdx.x;
    int cr = idx >> 6, kc = idx & 63;
    dst[(size_t)(c0 + cr) * 2048 + (k0 + kc)] = sm[kc][cr];
  }
}

// ---- segmentation v6: (t,b)-parallel, O(1)/thread bit math, ballot ranks ----
__global__ void k_seg(const int* __restrict__ dones, int* __restrict__ cnt,
                      int* __restrict__ rowlist, int* __restrict__ zlist,
                      int* __restrict__ chains){
  __shared__ unsigned long long sm_m[2];
  __shared__ int cntw[2][26];
  __shared__ int lbase[26];
  const int b = blockIdx.x, t = threadIdx.x;
  const int wv = t >> 6, lane = t & 63;
  bool pred = (t >= 1) && (dones[t*BB + b] != 0);
  unsigned long long bal = __ballot(pred);
  if (lane == 0) sm_m[wv] = bal;
  __syncthreads();
  const unsigned long long m0 = sm_m[0], m1 = sm_m[1];
  const bool d0 = (dones[b] != 0);
  int s, e;
  if (t < 64){
    unsigned long long msk = (t == 63) ? ~0ull : ((1ull << (t+1)) - 1);
    unsigned long long lo = m0 & msk;
    s = lo ? 63 - __builtin_clzll(lo) : 0;
    unsigned long long rem = m0 & ~msk;
    if (rem) e = __builtin_ctzll(rem);
    else if (m1) e = 64 + __builtin_ctzll(m1);
    else e = TT;
  } else {
    int u = t - 64;
    unsigned long long msk = (u == 63) ? ~0ull : ((1ull << (u+1)) - 1);
    unsigned long long hi = m1 & msk;
    if (hi) s = 64 + 63 - __builtin_clzll(hi);
    else s = m0 ? 63 - __builtin_clzll(m0) : 0;
    unsigned long long rem = m1 & ~msk;
    e = rem ? 64 + __builtin_ctzll(rem) : TT;
  }
  const int d = t - s;
  int my_d;
  if (d == 0)            my_d = (s == 0 && !d0) ? 0 : 24;
  else if (d < DPAR)     my_d = d;
  else if (d == DPAR)    my_d = 25;
  else                   my_d = 26;
  int my_rank = 0;
  for (int d2 = 0; d2 < 26; ++d2){
    unsigned long long mk = __ballot(my_d == d2);
    if (my_d == d2) my_rank = __popcll(mk & ((1ull << lane) - 1));
    if (lane == 0) cntw[wv][d2] = __popcll(mk);
  }
  __syncthreads();
  if (wv == 1 && my_d < 26) my_rank += cntw[0][my_d];
  if (t < 26){
    int tot = cntw[0][t] + cntw[1][t];
    lbase[t] = tot ? atomicAdd(&cnt[t], tot) : 0;
  }
  __syncthreads();
  if (my_d < 24){
    rowlist[my_d*BUCKCAP + lbase[my_d] + my_rank] = (t << 7) | b;
  } else if (my_d == 24){
    zlist[lbase[24] + my_rank] = (t << 7) | b;
  } else if (my_d == 25){
    int c = lbase[25] + my_rank;
    chains[c*3+0] = b; chains[c*3+1] = s; chains[c*3+2] = e - s;
  }
}

// ---- emb = relu(ws @ W_emb + b_emb): m97 + 2-phase dbuf, K=512 (8 kt) ----
__global__ __launch_bounds__(256)
void k_emb(const f16* __restrict__ A, const f16* __restrict__ Bt,
           const float* __restrict__ bias, f16* __restrict__ outb){
  __shared__ __attribute__((aligned(16))) char smem[65536];
  int tid = threadIdx.x;
  int w = tid >> 6, lane = tid & 63;
  int wm = w >> 1, wn = w & 1;
  int bid = blockIdx.x;                       // 1024 = 128 Mb x 8 Nb
  int vid = (bid & 7) * 128 + (bid >> 3);
  int Mb = (vid >> 3) * 128, Nb = (vid & 7) * 128;
  int la = lane & 15, lk = (lane >> 4) * 8;
  f32x4 acc[4][4] = {};
  int pr[4], pc16[4];
  #pragma unroll
  for (int q = 0; q < 4; ++q){
    int P = (w*4 + q)*1024 + lane*16;
    int r = P >> 7;
    pr[q] = r;
    pc16[q] = ((P & 127) ^ ((r & 7) << 4)) >> 4;
  }
  #pragma unroll
  for (int q = 0; q < 4; ++q){
    gload16(A  + (size_t)(Mb + pr[q])*OBSD + pc16[q]*8, smem + (w*4 + q)*1024);
    gload16(Bt + (size_t)(Nb + pr[q])*OBSD + pc16[q]*8, smem + 16384 + (w*4 + q)*1024);
  }
  __syncthreads();
  for (int kt = 0; kt < 8; ++kt){
    const int cb = (kt & 1) * 32768;
    if (kt + 1 < 8){
      const int pb = ((kt + 1) & 1) * 32768;
      #pragma unroll
      for (int q = 0; q < 4; ++q){
        gload16(A  + (size_t)(Mb + pr[q])*OBSD + (kt+1)*64 + pc16[q]*8,
                smem + pb + (w*4 + q)*1024);
        gload16(Bt + (size_t)(Nb + pr[q])*OBSD + (kt+1)*64 + pc16[q]*8,
                smem + pb + 16384 + (w*4 + q)*1024);
      }
    }
    #pragma unroll
    for (int kk = 0; kk < 64; kk += 32){
      f16x8 av[4], bv[4];
      #pragma unroll
      for (int m = 0; m < 4; ++m){
        int r = wm*64 + m*16 + la;
        av[m] = *reinterpret_cast<const f16x8*>(
            smem + cb + r*128 + (((kk + lk)*2) ^ ((r & 7) << 4)));
      }
      #pragma unroll
      for (int n = 0; n < 4; ++n){
        int r = wn*64 + n*16 + la;
        bv[n] = *reinterpret_cast<const f16x8*>(
            smem + cb + 16384 + r*128 + (((kk + lk)*2) ^ ((r & 7) << 4)));
      }
      #pragma unroll
      for (int m = 0; m < 4; ++m)
        #pragma unroll
        for (int n = 0; n < 4; ++n)
          acc[m][n] = mfma16(av[m], bv[n], acc[m][n]);
    }
    __syncthreads();
  }
  for (int mi = 0; mi < 4; ++mi) for (int ni = 0; ni < 4; ++ni){
    int col = Nb + wn*64 + ni*16 + la;
    float bb = bias[col];
    for (int i = 0; i < 4; ++i){
      int row = Mb + wm*64 + mi*16 + (lane >> 4)*4 + i;
      float v = acc[mi][ni][i] + bb;
      outb[(size_t)row * HID + col] = (f16)(v > 0.f ? v : 0.f);
    }
  }
}

// ---- xi = emb @ Wi + bi: m97 + 2-phase dbuf (128x128, BK=64, 16 kt) ----
__global__ __launch_bounds__(256)
void k_xi(const f16* __restrict__ A, const f16* __restrict__ Bt,
          const float* __restrict__ bias, f16* __restrict__ outb){
  __shared__ __attribute__((aligned(16))) char smem[65536];
  int tid = threadIdx.x;
  int w = tid >> 6, lane = tid & 63;
  int wm = w >> 1, wn = w & 1;
  int bid = blockIdx.x;                       // 3072 = 128 Mb x 24 Nb
  int vid = (bid & 7) * 384 + (bid >> 3);
  int Mb = (vid / 24) * 128, Nb = (vid % 24) * 128;
  int la = lane & 15, lk = (lane >> 4) * 8;
  f32x4 acc[4][4] = {};
  int pr[4], pc16[4];
  #pragma unroll
  for (int q = 0; q < 4; ++q){
    int P = (w*4 + q)*1024 + lane*16;
    int r = P >> 7;
    pr[q] = r;
    pc16[q] = ((P & 127) ^ ((r & 7) << 4)) >> 4;
  }
  #pragma unroll
  for (int q = 0; q < 4; ++q){
    gload16(A  + (size_t)(Mb + pr[q])*HID  + pc16[q]*8, smem + (w*4 + q)*1024);
    gload16(Bt + (size_t)(Nb + pr[q])*2048 + pc16[q]*8, smem + 16384 + (w*4 + q)*1024);
  }
  __syncthreads();
  for (int kt = 0; kt < 16; ++kt){
    const int cb = (kt & 1) * 32768;
    if (kt + 1 < 16){
      const int pb = ((kt + 1) & 1) * 32768;
      #pragma unroll
      for (int q = 0; q < 4; ++q){
        gload16(A  + (size_t)(Mb + pr[q])*HID  + (kt+1)*64 + pc16[q]*8,
                smem + pb + (w*4 + q)*1024);
        gload16(Bt + (size_t)(Nb + pr[q])*2048 + (kt+1)*64 + pc16[q]*8,
                smem + pb + 16384 + (w*4 + q)*1024);
      }
    }
    #pragma unroll
    for (int kk = 0; kk < 64; kk += 32){
      f16x8 av[4], bv[4];
      #pragma unroll
      for (int m = 0; m < 4; ++m){
        int r = wm*64 + m*16 + la;
        av[m] = *reinterpret_cast<const f16x8*>(
            smem + cb + r*128 + (((kk + lk)*2) ^ ((r & 7) << 4)));
      }
      #pragma unroll
      for (int n = 0; n < 4; ++n){
        int r = wn*64 + n*16 + la;
        bv[n] = *reinterpret_cast<const f16x8*>(
            smem + cb + 16384 + r*128 + (((kk + lk)*2) ^ ((r & 7) << 4)));
      }
      #pragma unroll
      for (int m = 0; m < 4; ++m)
        #pragma unroll
        for (int n = 0; n < 4; ++n)
          acc[m][n] = mfma16(av[m], bv[n], acc[m][n]);
    }
    __syncthreads();
  }
  for (int mi = 0; mi < 4; ++mi) for (int ni = 0; ni < 4; ++ni){
    int col = Nb + wn*64 + ni*16 + la;
    float bb = bias[col];
    for (int i = 0; i < 4; ++i){
      int row = Mb + wm*64 + mi*16 + (lane >> 4)*4 + i;
      outb[(size_t)row * 3072 + col] = (f16)(acc[mi][ni][i] + bb);
    }
  }
}

// ---- h-zero rows: h = (1-z)*n, straight from xi (no GEMM) ----
__global__ __launch_bounds__(256)
void k_h0(const int* __restrict__ cnt, const int* __restrict__ zlist,
          const f16* __restrict__ xi, const float* __restrict__ bhn_p,
          f16* __restrict__ y, float* __restrict__ hout){
  int nz = cnt[24];
  int tid = threadIdx.x;
  for (int ridx = blockIdx.x; ridx < nz; ridx += gridDim.x){
    int tb = zlist[ridx];
    int t = tb >> 7, b = tb & 127;
    size_t rb = ((size_t)t*BB + b) * 3072;
    int c0 = tid * 4;
    f16x4 xr = *reinterpret_cast<const f16x4*>(xi + rb + c0);
    f16x4 xz = *reinterpret_cast<const f16x4*>(xi + rb + 1024 + c0);
    f16x4 xn = *reinterpret_cast<const f16x4*>(xi + rb + 2048 + c0);
    f16x4 o;
    #pragma unroll
    for (int u = 0; u < 4; ++u){
      float r = 1.f / (1.f + expf(-(float)xr[u]));
      float z = 1.f / (1.f + expf(-(float)xz[u]));
      float n = tanhf((float)xn[u] + r * bhn_p[c0 + u]);
      float h = (1.f - z) * n;
      o[u] = (f16)h;
      if (t == TT - 1) hout[(size_t)b*HID + c0 + u] = h;
    }
    *reinterpret_cast<f16x4*>(y + ((size_t)t*BB + b)*HID + c0) = o;
  }
}

// ---- depth (small; used for j=0 and j>=3): 16 rows x 32 hcols/block ----
__global__ __launch_bounds__(512)
void k_depth(int j, const int* __restrict__ cnt, const int* __restrict__ rowlist_g,
             const f16* __restrict__ xi, const f16* __restrict__ bt2,
             const float* __restrict__ bhn_p, const float* __restrict__ hidden0,
             f16* __restrict__ y, float* __restrict__ hout){
  __shared__ __attribute__((aligned(16))) char smem[32768];
  const int count = cnt[j];
  if (count <= 0) return;
  const int* rowlist = rowlist_g + (size_t)j * BUCKCAP;
  const int tid = threadIdx.x;
  const int lane = tid & 63;
  const int w = tid >> 6;
  const int bid = blockIdx.x;
  const int la = lane & 15, lk = (lane >> 4) * 8;
  float* red = (float*)smem;
  const int vid = (bid & 7) * 128 + (bid >> 3);
  const int cs2 = vid >> 5;
  const int rgs = vid & 31;
  const int cg = w >> 2, kq = w & 3;
  const f16* Bq0 = bt2 + (size_t)(          cs2*32 + cg*16 + la)*2048 + 1024 + kq*256 + lk;
  const f16* Bq1 = bt2 + (size_t)(1024 +    cs2*32 + cg*16 + la)*2048 + 1024 + kq*256 + lk;
  const f16* Bq2 = bt2 + (size_t)(2048 +    cs2*32 + cg*16 + la)*2048 + 1024 + kq*256 + lk;
  const int es = tid >> 8, ei = (tid >> 6) & 3, elane = tid & 63;
  const int erow_l = ((elane >> 4) << 2) + ei;
  const int ecol = cs2*32 + es*16 + (elane & 15);
  const float bh = bhn_p[ecol];
  const int nrg = (count + 15) >> 4;
  for (int rg = rgs; rg < nrg; rg += 32){
    __syncthreads();
    #pragma unroll
    for (int it = 0; it < 4; ++it){
      int idx = tid + it*512;
      int r = idx >> 7, part = idx & 127;
      int ridx = rg*16 + r;
      int tb = (ridx < count) ? rowlist[ridx] : -1;
      float4 v = {0.f, 0.f, 0.f, 0.f};
      if (tb >= 0){
        int t = tb >> 7, bb_ = tb & 127;
        if (j > 0){
          v = *reinterpret_cast<const float4*>(y + ((size_t)(t-1)*BB + bb_)*HID + part*8);
        } else {
          const float* s = hidden0 + (size_t)bb_*HID + part*8;
          float4 a0 = *reinterpret_cast<const float4*>(s);
          float4 a1 = *reinterpret_cast<const float4*>(s + 4);
          f16 h8[8] = {(f16)a0.x,(f16)a0.y,(f16)a0.z,(f16)a0.w,
                       (f16)a1.x,(f16)a1.y,(f16)a1.z,(f16)a1.w};
          v = *reinterpret_cast<float4*>(h8);
        }
      }
      *reinterpret_cast<float4*>(smem + ((r*2048 + part*16) ^ ((r & 7) << 4))) = v;
    }
    __syncthreads();
    f32x4 a0 = {}, a1 = {}, a2 = {};
    #pragma unroll
    for (int kk = 0; kk < 256; kk += 32){
      int k = kq*256 + kk + lk;
      f16x8 av = *reinterpret_cast<const f16x8*>(
          smem + ((la*2048 + k*2) ^ ((la & 7) << 4)));
      a0 = mfma16(av, *reinterpret_cast<const f16x8*>(Bq0 + kk), a0);
      a1 = mfma16(av, *reinterpret_cast<const f16x8*>(Bq1 + kk), a1);
      a2 = mfma16(av, *reinterpret_cast<const f16x8*>(Bq2 + kk), a2);
    }
    __syncthreads();
    #pragma unroll
    for (int i = 0; i < 4; ++i){
      red[((((cg*4 + kq)*3 + 0)*64 + lane)*5) + i] = a0[i];
      red[((((cg*4 + kq)*3 + 1)*64 + lane)*5) + i] = a1[i];
      red[((((cg*4 + kq)*3 + 2)*64 + lane)*5) + i] = a2[i];
    }
    __syncthreads();
    int ridx = rg*16 + erow_l;
    if (ridx < count){
      int tb = rowlist[ridx];
      int t = tb >> 7, bb_ = tb & 127;
      float hr = 0.f, hz = 0.f, hn = 0.f;
      #pragma unroll
      for (int kq2 = 0; kq2 < 4; ++kq2){
        hr += red[((((es*4 + kq2)*3 + 0)*64 + elane)*5) + ei];
        hz += red[((((es*4 + kq2)*3 + 1)*64 + elane)*5) + ei];
        hn += red[((((es*4 + kq2)*3 + 2)*64 + elane)*5) + ei];
      }
      size_t rb = ((size_t)t*BB + bb_)*3072 + ecol;
      float hold;
      if (j > 0) hold = (float)y[((size_t)(t-1)*BB + bb_)*HID + ecol];
      else       hold = hidden0[(size_t)bb_*HID + ecol];
      float r = 1.f / (1.f + expf(-((float)xi[rb]        + hr)));
      float z = 1.f / (1.f + expf(-((float)xi[rb + 1024] + hz)));
      float n = tanhf((float)xi[rb + 2048] + r * (hn + bh));
      float hnew = (1.f - z) * n + z * hold;
      y[((size_t)t*BB + bb_)*HID + ecol] = (f16)hnew;
      if (t == TT - 1) hout[(size_t)bb_*HID + ecol] = hnew;
    }
  }
}

// ---- depth GEMM (j=1,2): hh[ridx][3072] = h_prev @ Wh; m97 template.
// Identity block mapping: early-exit grids must spread active blocks over
// all XCDs (round-24 chunked swizzle left XCDs 5-7 idle for count~4100). ----
__global__ __launch_bounds__(256)
void k_depth_gemm(int j, const int* __restrict__ cnt, const int* __restrict__ rowlist_g,
                  const f16* __restrict__ y, const f16* __restrict__ bt2,
                  f16* __restrict__ hh){
  __shared__ __attribute__((aligned(16))) char smem[65536];
  const int count = cnt[j];
  if (count <= 0) return;
  const int* rowlist = rowlist_g + (size_t)j * BUCKCAP;
  int tid = threadIdx.x;
  int w = tid >> 6, lane = tid & 63;
  int wm = w >> 1, wn = w & 1;
  int bid = blockIdx.x;                       // 1536 = 64 Mt x 24 Nb, identity
  int vid = bid;                              // Mb-major: active blocks hit all XCDs
  int Mb = (vid / 24) * 128, Nb = (vid % 24) * 128;
  if (Mb >= count) return;
  int la = lane & 15, lk = (lane >> 4) * 8;
  f32x4 acc[4][4] = {};
  int pr[4], pc16[4];
  const f16* rp[4];
  #pragma unroll
  for (int q = 0; q < 4; ++q){
    int P = (w*4 + q)*1024 + lane*16;
    int r = P >> 7;
    pr[q] = r;
    pc16[q] = ((P & 127) ^ ((r & 7) << 4)) >> 4;
    int ridx = Mb + r; if (ridx >= count) ridx = count - 1;
    int tb = rowlist[ridx];
    rp[q] = y + ((size_t)((tb >> 7) - 1)*BB + (tb & 127))*HID;
  }
  #pragma unroll
  for (int q = 0; q < 4; ++q){
    gload16(rp[q] + pc16[q]*8, smem + (w*4 + q)*1024);
    gload16(bt2 + (size_t)(Nb + pr[q])*2048 + 1024 + pc16[q]*8,
            smem + 16384 + (w*4 + q)*1024);
  }
  __syncthreads();
  for (int kt = 0; kt < 16; ++kt){
    const int cb = (kt & 1) * 32768;
    if (kt + 1 < 16){
      const int pb = ((kt + 1) & 1) * 32768;
      #pragma unroll
      for (int q = 0; q < 4; ++q){
        gload16(rp[q] + (kt+1)*64 + pc16[q]*8, smem + pb + (w*4 + q)*1024);
        gload16(bt2 + (size_t)(Nb + pr[q])*2048 + 1024 + (kt+1)*64 + pc16[q]*8,
                smem + pb + 16384 + (w*4 + q)*1024);
      }
    }
    #pragma unroll
    for (int kk = 0; kk < 64; kk += 32){
      f16x8 av[4], bv[4];
      #pragma unroll
      for (int m = 0; m < 4; ++m){
        int r = wm*64 + m*16 + la;
        av[m] = *reinterpret_cast<const f16x8*>(
            smem + cb + r*128 + (((kk + lk)*2) ^ ((r & 7) << 4)));
      }
      #pragma unroll
      for (int n = 0; n < 4; ++n){
        int r = wn*64 + n*16 + la;
        bv[n] = *reinterpret_cast<const f16x8*>(
            smem + cb + 16384 + r*128 + (((kk + lk)*2) ^ ((r & 7) << 4)));
      }
      #pragma unroll
      for (int m = 0; m < 4; ++m)
        #pragma unroll
        for (int n = 0; n < 4; ++n)
          acc[m][n] = mfma16(av[m], bv[n], acc[m][n]);
    }
    __syncthreads();
  }
  for (int mi = 0; mi < 4; ++mi) for (int ni = 0; ni < 4; ++ni){
    int col = Nb + wn*64 + ni*16 + la;
    for (int i = 0; i < 4; ++i){
      int row = Mb + wm*64 + mi*16 + (lane >> 4)*4 + i;
      hh[(size_t)row * 3072 + col] = (f16)acc[mi][ni][i];
    }
  }
}

// ---- depth epilogue (j=1,2): gates from xi + hh, write y[t] ----
__global__ __launch_bounds__(256)
void k_depth_ep(int j, const int* __restrict__ cnt, const int* __restrict__ rowlist_g,
                const f16* __restrict__ hh, const f16* __restrict__ xi,
                const float* __restrict__ bhn_p, f16* __restrict__ y,
                float* __restrict__ hout){
  const int count = cnt[j];
  const int* rowlist = rowlist_g + (size_t)j * BUCKCAP;
  int tid = threadIdx.x;
  int c0 = tid * 4;
  for (int ridx = blockIdx.x; ridx < count; ridx += gridDim.x){
    int tb = rowlist[ridx];
    int t = tb >> 7, b = tb & 127;
    size_t hb = (size_t)ridx * 3072;
    f16x4 hr4 = *reinterpret_cast<const f16x4*>(hh + hb + c0);
    f16x4 hz4 = *reinterpret_cast<const f16x4*>(hh + hb + 1024 + c0);
    f16x4 hn4 = *reinterpret_cast<const f16x4*>(hh + hb + 2048 + c0);
    size_t rb = ((size_t)t*BB + b)*3072 + c0;
    f16x4 xr4 = *reinterpret_cast<const f16x4*>(xi + rb);
    f16x4 xz4 = *reinterpret_cast<const f16x4*>(xi + rb + 1024);
    f16x4 xn4 = *reinterpret_cast<const f16x4*>(xi + rb + 2048);
    f16x4 ho4 = *reinterpret_cast<const f16x4*>(y + ((size_t)(t-1)*BB + b)*HID + c0);
    f16x4 o;
    #pragma unroll
    for (int u = 0; u < 4; ++u){
      float r = 1.f / (1.f + expf(-((float)xr4[u] + (float)hr4[u])));
      float z = 1.f / (1.f + expf(-((float)xz4[u] + (float)hz4[u])));
      float n = tanhf((float)xn4[u] + r * ((float)hn4[u] + bhn_p[c0 + u]));
      float hnew = (1.f - z) * n + z * (float)ho4[u];
      o[u] = (f16)hnew;
      if (t == TT - 1) hout[(size_t)b*HID + c0 + u] = hnew;
    }
    *reinterpret_cast<f16x4*>(y + ((size_t)t*BB + b)*HID + c0) = o;
  }
}

// ---- sequential tail for chains longer than DPAR (empty for this seed) ----
__global__ __launch_bounds__(256)
void k_tail(const int* __restrict__ cnt, const int* __restrict__ chains,
            const f16* __restrict__ xi, const f16* __restrict__ bt2,
            const float* __restrict__ bhn_p, f16* __restrict__ y,
            float* __restrict__ hout){
  int n = cnt[25];
  __shared__ f16 hs[1024];
  int tid = threadIdx.x;
  for (int c = blockIdx.x; c < n; c += gridDim.x){
    int b = chains[c*3], t0 = chains[c*3+1], len = chains[c*3+2];
    for (int i = tid; i < 1024; i += 256)
      hs[i] = y[((size_t)(t0 + DPAR - 1)*BB + b)*HID + i];
    __syncthreads();
    for (int t = t0 + DPAR; t < t0 + len; ++t){
      float tmp[4];
      #pragma unroll
      for (int u = 0; u < 4; ++u){
        int col = tid*4 + u;
        float s_r = 0.f, s_z = 0.f, s_hn = 0.f;
        const f16* wr = bt2 + (size_t)col*2048 + 1024;
        const f16* wz = bt2 + (size_t)(1024+col)*2048 + 1024;
        const f16* wn = bt2 + (size_t)(2048+col)*2048 + 1024;
        for (int q = 0; q < 128; ++q){
          f16x8 hv = *reinterpret_cast<const f16x8*>(&hs[q*8]);
          f16x8 wrh = *reinterpret_cast<const f16x8*>(wr + q*8);
          f16x8 wzh = *reinterpret_cast<const f16x8*>(wz + q*8);
          f16x8 wnh = *reinterpret_cast<const f16x8*>(wn + q*8);
          #pragma unroll
          for (int e = 0; e < 8; ++e){
            float hh_ = (float)hv[e];
            s_r  += hh_*(float)wrh[e];
            s_z  += hh_*(float)wzh[e];
            s_hn += hh_*(float)wnh[e];
          }
        }
        size_t rb = ((size_t)t*BB + b)*3072 + col;
        float r = 1.f / (1.f + expf(-((float)xi[rb] + s_r)));
        float z = 1.f / (1.f + expf(-((float)xi[rb + 1024] + s_z)));
        float nn = tanhf((float)xi[rb + 2048] + r * (s_hn + bhn_p[col]));
        float hold = (float)hs[col];
        float hnew = (1.f - z) * nn + z * hold;
        y[((size_t)t*BB + b)*HID + col] = (f16)hnew;
        if (t == TT - 1) hout[(size_t)b*HID + col] = hnew;
        tmp[u] = hnew;
      }
      __syncthreads();
      #pragma unroll
      for (int u = 0; u < 4; ++u) hs[tid*4 + u] = (f16)tmp[u];
      __syncthreads();
    }
    __syncthreads();
  }
}

// ---- critic: m97 + 2-phase dbuf (128x128, BK=64, 16 kt) + value fusion ----
__global__ __launch_bounds__(256)
void k_critic(const f16* __restrict__ Y, const f16* __restrict__ Bt,
              const float* __restrict__ b1, const float* __restrict__ W2,
              float* __restrict__ vpart){
  __shared__ __attribute__((aligned(16))) char smem[65536];
  int tid = threadIdx.x;
  int w = tid >> 6, lane = tid & 63;
  int wm = w >> 1, wn = w & 1;
  int bid = blockIdx.x;
  int vid = (bid & 7) * 128 + (bid >> 3);
  int Mb = (vid >> 3) * 128, Nb = (vid & 7) * 128;
  int la = lane & 15, lk = (lane >> 4) * 8;
  f32x4 acc[4][4] = {};
  int pr[4], pc16[4];
  #pragma unroll
  for (int q = 0; q < 4; ++q){
    int P = (w*4 + q)*1024 + lane*16;
    int r = P >> 7;
    pr[q] = r;
    pc16[q] = ((P & 127) ^ ((r & 7) << 4)) >> 4;
  }
  #pragma unroll
  for (int q = 0; q < 4; ++q){
    gload16(Y  + (size_t)(Mb + pr[q])*HID + pc16[q]*8, smem + (w*4 + q)*1024);
    gload16(Bt + (size_t)(Nb + pr[q])*HID + pc16[q]*8, smem + 16384 + (w*4 + q)*1024);
  }
  __syncthreads();
  for (int kt = 0; kt < 16; ++kt){
    const int cb = (kt & 1) * 32768;
    if (kt + 1 < 16){
      const int pb = ((kt + 1) & 1) * 32768;
      #pragma unroll
      for (int q = 0; q < 4; ++q){
        gload16(Y  + (size_t)(Mb + pr[q])*HID + (kt+1)*64 + pc16[q]*8,
                smem + pb + (w*4 + q)*1024);
        gload16(Bt + (size_t)(Nb + pr[q])*HID + (kt+1)*64 + pc16[q]*8,
                smem + pb + 16384 + (w*4 + q)*1024);
      }
    }
    #pragma unroll
    for (int kk = 0; kk < 64; kk += 32){
      f16x8 av[4], bv[4];
      #pragma unroll
      for (int m = 0; m < 4; ++m){
        int r = wm*64 + m*16 + la;
        av[m] = *reinterpret_cast<const f16x8*>(
            smem + cb + r*128 + (((kk + lk)*2) ^ ((r & 7) << 4)));
      }
      #pragma unroll
      for (int n = 0; n < 4; ++n){
        int r = wn*64 + n*16 + la;
        bv[n] = *reinterpret_cast<const f16x8*>(
            smem + cb + 16384 + r*128 + (((kk + lk)*2) ^ ((r & 7) << 4)));
      }
      #pragma unroll
      for (int m = 0; m < 4; ++m)
        #pragma unroll
        for (int n = 0; n < 4; ++n)
          acc[m][n] = mfma16(av[m], bv[n], acc[m][n]);
    }
    __syncthreads();
  }
  __shared__ float vs[2][64][2];
  float p[4][4];
  for (int mi = 0; mi < 4; ++mi) for (int i = 0; i < 4; ++i) p[mi][i] = 0.f;
  for (int ni = 0; ni < 4; ++ni){
    int col = Nb + wn*64 + ni*16 + la;
    float bb = b1[col], w2 = W2[col];
    for (int mi = 0; mi < 4; ++mi)
      for (int i = 0; i < 4; ++i){
        float c = acc[mi][ni][i] + bb;
        p[mi][i] += (c > 0.f ? c : 0.f) * w2;
      }
  }
  for (int mi = 0; mi < 4; ++mi) for (int i = 0; i < 4; ++i){
    float s = p[mi][i];
    s += __shfl_xor(s, 1); s += __shfl_xor(s, 2);
    s += __shfl_xor(s, 4); s += __shfl_xor(s, 8);
    p[mi][i] = s;
  }
  if (la == 0){
    int q = lane >> 4;
    for (int mi = 0; mi < 4; ++mi)
      for (int i = 0; i < 4; ++i)
        vs[wm][mi*16 + q*4 + i][wn] = p[mi][i];
  }
  __syncthreads();
  if (threadIdx.x < 128){
    int rw = threadIdx.x;
    float s = vs[rw >> 6][rw & 63][0] + vs[rw >> 6][rw & 63][1];
    vpart[(size_t)(Nb >> 7) * (TT*BB) + Mb + rw] = s;
  }
}

__global__ void k_vreduce(const float* __restrict__ vpart, const float* __restrict__ b2,
                          float* __restrict__ outv){
  int m = blockIdx.x * 256 + threadIdx.x;
  float s = b2[0];
  for (int nb = 0; nb < 8; ++nb) s += vpart[(size_t)nb * (TT*BB) + m];
  outv[m] = s;
}

extern "C" void kernel_launch(void* const* d_in, const int* in_sizes, int n_in,
                              void* d_out, int out_size, void* d_ws, size_t ws_size,
                              hipStream_t stream){
  const float* hidden = (const float*)d_in[0];
  const float* world  = (const float*)d_in[1];
  const int*   dones  = (const int*)d_in[2];
  const float* W_emb  = (const float*)d_in[3];
  const float* b_emb  = (const float*)d_in[4];
  const float* Wi     = (const float*)d_in[5];
  const float* bi     = (const float*)d_in[6];
  const float* Wh     = (const float*)d_in[7];
  const float* bhn    = (const float*)d_in[8];
  const float* W1     = (const float*)d_in[9];
  const float* b1     = (const float*)d_in[10];
  const float* W2     = (const float*)d_in[11];
  const float* b2     = (const float*)d_in[12];
  float* out = (float*)d_out;

  char* p = (char*)d_ws;
  auto alloc = [&](size_t bytes) -> char* {
    char* r = p; p += (bytes + 255) & ~(size_t)255; return r;
  };
  f16*   ws16   = (f16*)alloc((size_t)TT*BB*OBSD*2);     // 16 MB   } hh (50.3 MB)
  f16*   wembt  = (f16*)alloc((size_t)HID*OBSD*2);       // 1 MB    } overlays these
  f16*   emb16  = (f16*)alloc((size_t)TT*BB*HID*2);      // 33.5 MB } (dead post-k_xi)
  f16*   bt2    = (f16*)alloc((size_t)3072*2048*2);      // 12.6 MB
  f16*   w1t    = (f16*)alloc((size_t)HID*HID*2);        // 2 MB
  f16*   xi16   = (f16*)alloc((size_t)TT*BB*3072*2);     // 100.7 MB
  f16*   ybuf   = (f16*)alloc((size_t)TT*BB*HID*2);      // 33.5 MB
  float* vpart  = (float*)alloc((size_t)8*TT*BB*4);      // 0.5 MB
  int*   cnt    = (int*)alloc(26*4);
  int*   rowlist= (int*)alloc((size_t)DPAR*BUCKCAP*4);   // 1.57 MB
  int*   zlist  = (int*)alloc((size_t)BUCKCAP*4);
  int*   chains = (int*)alloc((size_t)1024*3*4);
  if ((size_t)(p - (char*)d_ws) > ws_size) return;
  f16* hh = (f16*)d_ws;   // 8192 x 3072 f16 = 50.3 MB, overlays ws16..emb16

  hipMemsetAsync(cnt, 0, 26*4, stream);

  // preps (+ segmentation, depends only on dones)
  k_ws_to_f16<<<(TT*BB*OBSD/4 + 255)/256, 256, 0, stream>>>(world, ws16, TT*BB*OBSD/4);
  k_prep_bt<<<dim3(OBSD/64, HID/64), 256, 0, stream>>>(W_emb, 1024, wembt, OBSD);
  k_prep_bt2<<<dim3(2048/64, 3072/64), 256, 0, stream>>>(Wi, Wh, bt2);
  k_prep_bt<<<dim3(HID/64, HID/64), 256, 0, stream>>>(W1, 1024, w1t, HID);
  k_seg<<<128, 128, 0, stream>>>(dones, cnt, rowlist, zlist, chains);

  // parallel GEMMs
  k_emb<<<1024, 256, 0, stream>>>(ws16, wembt, b_emb, emb16);
  k_xi<<<3072, 256, 0, stream>>>(emb16, bt2, bi, xi16);

  // h-zero rows (no GEMM) + depth-parallel GRU scan + tail
  k_h0<<<2048, 256, 0, stream>>>(cnt, zlist, xi16, bhn, ybuf, out);
  for (int j = 0; j < DPAR; ++j){
    if (j == 1 || j == 2){
      k_depth_gemm<<<1536, 256, 0, stream>>>(j, cnt, rowlist, ybuf, bt2, hh);
      k_depth_ep<<<4096, 256, 0, stream>>>(j, cnt, rowlist, hh, xi16, bhn, ybuf, out);
    } else {
      k_depth<<<1024, 512, 0, stream>>>(j, cnt, rowlist, xi16, bt2, bhn,
                                        hidden, ybuf, out);
    }
  }
  k_tail<<<128, 256, 0, stream>>>(cnt, chains, xi16, bt2, bhn, ybuf, out);

  // critic head + value
  k_critic<<<1024, 256, 0, stream>>>(ybuf, w1t, b1, W2, vpart);
  k_vreduce<<<TT*BB/256, 256, 0, stream>>>(vpart, b2, out + (size_t)BB*HID);
}